// Round 1
// baseline (7699.786 us; speedup 1.0000x reference)
//
#include <hip/hip_runtime.h>

constexpr int B = 32, N = 325, E = 64, S = 12, HOPS = 3;
constexpr int BN  = B * N;        // 10400
constexpr int BNE = B * N * E;    // 665600
constexpr int NT  = (N + 31) / 32; // 11
constexpr float SCALE_INV = 0.125f; // 1/sqrt(E)

// ---------------- adp = softmax(relu(nv1 @ nv2^T)) ----------------
__global__ __launch_bounds__(256) void adp_kernel(const float* __restrict__ nv1,
                                                  const float* __restrict__ nv2,
                                                  float* __restrict__ adp) {
  int n = blockIdx.x;
  __shared__ float row[E];
  __shared__ float buf[N];
  __shared__ float red[256];
  int tid = threadIdx.x;
  if (tid < E) row[tid] = nv1[n * E + tid];
  __syncthreads();
  float lmax = -1e30f;
  for (int m = tid; m < N; m += 256) {
    const float* v2 = nv2 + (size_t)m * E;
    float s = 0.f;
#pragma unroll
    for (int e = 0; e < E; ++e) s += row[e] * v2[e];
    s = fmaxf(s, 0.f);
    buf[m] = s;
    lmax = fmaxf(lmax, s);
  }
  red[tid] = lmax;
  __syncthreads();
  for (int off = 128; off > 0; off >>= 1) {
    if (tid < off) red[tid] = fmaxf(red[tid], red[tid + off]);
    __syncthreads();
  }
  float mx = red[0];
  __syncthreads();
  float lsum = 0.f;
  for (int m = tid; m < N; m += 256) {
    float ev = expf(buf[m] - mx);
    buf[m] = ev;
    lsum += ev;
  }
  red[tid] = lsum;
  __syncthreads();
  for (int off = 128; off > 0; off >>= 1) {
    if (tid < off) red[tid] += red[tid + off];
    __syncthreads();
  }
  float inv = 1.f / red[0];
  for (int m = tid; m < N; m += 256) adp[(size_t)n * N + m] = buf[m] * inv;
}

// ---------------- out[r][e'] (+)= sum_e in[r][e] * W[e][e']  (E x E) ----------------
__global__ __launch_bounds__(256) void rowmm_kernel(const float* __restrict__ in,
                                                    const float* __restrict__ W,
                                                    const float* __restrict__ bias,
                                                    float* __restrict__ out,
                                                    int accum) {
  __shared__ float Wl[E][E + 1];
  __shared__ float rbuf[4][E];
  int tid = threadIdx.x;
  for (int idx = tid; idx < E * E; idx += 256) Wl[idx >> 6][idx & 63] = W[idx];
  __syncthreads();
  int w = tid >> 6, l = tid & 63;
  int rpb = (BN + gridDim.x - 1) / gridDim.x;
  int r0 = blockIdx.x * rpb;
  int r1 = min(r0 + rpb, BN);
  for (int r = r0 + w; r < r1; r += 4) {
    rbuf[w][l] = in[(size_t)r * E + l];
    float acc = accum ? out[(size_t)r * E + l] : (bias ? bias[l] : 0.f);
#pragma unroll
    for (int e = 0; e < E; ++e) acc += rbuf[w][e] * Wl[e][l];
    out[(size_t)r * E + l] = acc;
  }
}

// ---------------- out[b,n,e] = sum_m A[n,m] * X[b,m,e]   (A shared across b) ----------------
__global__ __launch_bounds__(256) void bmm_kernel(const float* __restrict__ A,
                                                  const float* __restrict__ X,
                                                  float* __restrict__ out) {
  int b = blockIdx.x / NT, rt = blockIdx.x % NT;
  int n0 = rt * 32, nrows = min(32, N - n0);
  __shared__ float Ar[32][N + 1];
  __shared__ float tile[64][E];
  int tid = threadIdx.x, w = tid >> 6, l = tid & 63;
  for (int idx = tid; idx < nrows * N; idx += 256) {
    int r = idx / N, m = idx - r * N;
    Ar[r][m] = A[(size_t)(n0 + r) * N + m];
  }
  float acc[8];
#pragma unroll
  for (int r = 0; r < 8; ++r) acc[r] = 0.f;
  int ti = tid >> 2, c0 = (tid & 3) * 16;
  for (int mt = 0; mt < 6; ++mt) {
    int m0 = mt * 64, mv = min(64, N - m0);
    __syncthreads();
    if (ti < mv) {
      const float4* src = (const float4*)(X + ((size_t)b * N + m0 + ti) * E + c0);
      float4 a0 = src[0], a1 = src[1], a2 = src[2], a3 = src[3];
      float4* dst = (float4*)&tile[ti][c0];
      dst[0] = a0; dst[1] = a1; dst[2] = a2; dst[3] = a3;
    }
    __syncthreads();
    for (int i = 0; i < mv; ++i) {
      float t = tile[i][l];
#pragma unroll
      for (int r = 0; r < 8; ++r) acc[r] += Ar[w * 8 + r][m0 + i] * t;
    }
  }
#pragma unroll
  for (int r = 0; r < 8; ++r) {
    int rr = w * 8 + r;
    if (rr < nrows) out[((size_t)b * N + n0 + rr) * E + l] = acc[r];
  }
}

// ---------------- fused: energy -> softmax -> score@Z + C0 ; also sentinel ----------------
__global__ __launch_bounds__(256) void attn_kernel(const float* __restrict__ u,
                                                   const float* __restrict__ key,
                                                   const float* __restrict__ kms,
                                                   const float* __restrict__ Z,
                                                   const float* __restrict__ C0,
                                                   float* __restrict__ gpre,
                                                   float* __restrict__ sent) {
  int b = blockIdx.x / NT, rt = blockIdx.x % NT;
  int n0 = rt * 32, nrows = min(32, N - n0);
  __shared__ float uT[32][E];
  __shared__ float tile[64][E + 1];
  __shared__ float prob[32][N + 1];
  int tid = threadIdx.x, w = tid >> 6, l = tid & 63;
  for (int idx = tid; idx < nrows * E; idx += 256)
    uT[idx >> 6][idx & 63] = u[((size_t)b * N + n0) * E + idx];
  __syncthreads();
  // sentinel: sent[b,n] = dot(u_row, kms_row)/8
#pragma unroll
  for (int rr = 0; rr < 8; ++rr) {
    int r = w * 8 + rr;
    if (r < nrows) {
      float v = uT[r][l] * kms[((size_t)b * N + n0 + r) * E + l];
#pragma unroll
      for (int off = 32; off > 0; off >>= 1) v += __shfl_xor(v, off);
      if (l == 0) sent[(size_t)b * N + n0 + r] = v * SCALE_INV;
    }
  }
  int ti = tid >> 2, c0 = (tid & 3) * 16;
  // energy pass: lane l handles column m = m0 + l
  for (int mt = 0; mt < 6; ++mt) {
    int m0 = mt * 64, mv = min(64, N - m0);
    __syncthreads();
    if (ti < mv) {
      const float4* src = (const float4*)(key + ((size_t)b * N + m0 + ti) * E + c0);
      float4 a0 = src[0], a1 = src[1], a2 = src[2], a3 = src[3];
      float* d = &tile[ti][c0];
      d[0]=a0.x; d[1]=a0.y; d[2]=a0.z; d[3]=a0.w;
      d[4]=a1.x; d[5]=a1.y; d[6]=a1.z; d[7]=a1.w;
      d[8]=a2.x; d[9]=a2.y; d[10]=a2.z; d[11]=a2.w;
      d[12]=a3.x; d[13]=a3.y; d[14]=a3.z; d[15]=a3.w;
    }
    __syncthreads();
    float eacc[8];
#pragma unroll
    for (int r = 0; r < 8; ++r) eacc[r] = 0.f;
#pragma unroll
    for (int e = 0; e < E; ++e) {
      float t = tile[l][e];
#pragma unroll
      for (int r = 0; r < 8; ++r) eacc[r] += uT[w * 8 + r][e] * t;
    }
    if (m0 + l < N) {
#pragma unroll
      for (int r = 0; r < 8; ++r)
        if (w * 8 + r < nrows) prob[w * 8 + r][m0 + l] = eacc[r] * SCALE_INV;
    }
  }
  __syncthreads();
  // softmax per row (each wave owns its 8 rows)
  float rsum[8];
#pragma unroll
  for (int rr = 0; rr < 8; ++rr) {
    int r = w * 8 + rr;
    rsum[rr] = 1.f;
    if (r < nrows) {
      float v[6];
      float mx = -1e30f;
#pragma unroll
      for (int k = 0; k < 6; ++k) {
        int m = l + 64 * k;
        v[k] = (m < N) ? prob[r][m] : -1e30f;
        mx = fmaxf(mx, v[k]);
      }
#pragma unroll
      for (int off = 32; off > 0; off >>= 1) mx = fmaxf(mx, __shfl_xor(mx, off));
      float s = 0.f;
#pragma unroll
      for (int k = 0; k < 6; ++k) {
        int m = l + 64 * k;
        if (m < N) { float ev = expf(v[k] - mx); prob[r][m] = ev; s += ev; }
      }
#pragma unroll
      for (int off = 32; off > 0; off >>= 1) s += __shfl_xor(s, off);
      rsum[rr] = s;
    }
  }
  // PV pass: acc[r] = sum_m p[r][m] * Z[b,m,l]
  float acc[8];
#pragma unroll
  for (int r = 0; r < 8; ++r) acc[r] = 0.f;
  for (int mt = 0; mt < 6; ++mt) {
    int m0 = mt * 64, mv = min(64, N - m0);
    __syncthreads();
    if (ti < mv) {
      const float4* src = (const float4*)(Z + ((size_t)b * N + m0 + ti) * E + c0);
      float4 a0 = src[0], a1 = src[1], a2 = src[2], a3 = src[3];
      float* d = &tile[ti][c0];
      d[0]=a0.x; d[1]=a0.y; d[2]=a0.z; d[3]=a0.w;
      d[4]=a1.x; d[5]=a1.y; d[6]=a1.z; d[7]=a1.w;
      d[8]=a2.x; d[9]=a2.y; d[10]=a2.z; d[11]=a2.w;
      d[12]=a3.x; d[13]=a3.y; d[14]=a3.z; d[15]=a3.w;
    }
    __syncthreads();
    for (int i = 0; i < mv; ++i) {
      float t = tile[i][l];
#pragma unroll
      for (int r = 0; r < 8; ++r) acc[r] += prob[w * 8 + r][m0 + i] * t;
    }
  }
#pragma unroll
  for (int rr = 0; rr < 8; ++rr) {
    int r = w * 8 + rr;
    if (r < nrows) {
      size_t gi = ((size_t)b * N + n0 + r) * E + l;
      gpre[gi] = acc[rr] / rsum[rr] + C0[gi];
    }
  }
}

// ---------------- GRU cell (OD=1 input path) ----------------
__global__ __launch_bounds__(256) void gru_kernel(float* __restrict__ h,
                                                  const float* __restrict__ prev,
                                                  const float* __restrict__ wih,
                                                  const float* __restrict__ whh,
                                                  const float* __restrict__ bih,
                                                  const float* __restrict__ bhh,
                                                  float* __restrict__ u) {
  __shared__ float W[3 * E][E + 1];
  __shared__ float hrow[4][E];
  int tid = threadIdx.x, w = tid >> 6, l = tid & 63;
  for (int idx = tid; idx < 3 * E * E; idx += 256) W[idx >> 6][idx & 63] = whh[idx];
  __syncthreads();
  float wi0 = wih[l], wi1 = wih[64 + l], wi2 = wih[128 + l];
  float bi0 = bih[l], bi1 = bih[64 + l], bi2 = bih[128 + l];
  float bh0 = bhh[l], bh1 = bhh[64 + l], bh2 = bhh[128 + l];
  int nw = gridDim.x * 4, wid = blockIdx.x * 4 + w;
  for (int row = wid; row < BN; row += nw) {
    float hv = h[(size_t)row * E + l];
    hrow[w][l] = hv;
    float g0 = bh0, g1 = bh1, g2 = bh2;
#pragma unroll
    for (int e = 0; e < E; ++e) {
      float hh = hrow[w][e];
      g0 += hh * W[l][e];
      g1 += hh * W[64 + l][e];
      g2 += hh * W[128 + l][e];
    }
    float pv = prev[row];
    float i0 = pv * wi0 + bi0;
    float i1 = pv * wi1 + bi1;
    float i2 = pv * wi2 + bi2;
    float r = 1.f / (1.f + expf(-(i0 + g0)));
    float z = 1.f / (1.f + expf(-(i1 + g1)));
    float nn = tanhf(i2 + r * g2);
    float hn = (1.f - z) * nn + z * hv;
    h[(size_t)row * E + l] = hn;
    u[(size_t)row * E + l] = hn;
  }
}

// ---------------- BN batch stats per node n over (B,E) ----------------
__global__ __launch_bounds__(256) void bnstats_kernel(const float* __restrict__ gpre,
                                                      float* __restrict__ stats) {
  int n = blockIdx.x;
  int tid = threadIdx.x;
  float s = 0.f, ss = 0.f;
  for (int idx = tid; idx < B * E; idx += 256) {
    int b = idx >> 6, e = idx & 63;
    float v = gpre[((size_t)b * N + n) * E + e];
    s += v; ss += v * v;
  }
  __shared__ float r1[256], r2[256];
  r1[tid] = s; r2[tid] = ss;
  __syncthreads();
  for (int off = 128; off > 0; off >>= 1) {
    if (tid < off) { r1[tid] += r1[tid + off]; r2[tid] += r2[tid + off]; }
    __syncthreads();
  }
  if (tid == 0) {
    float mean = r1[0] / (float)(B * E);
    float var = r2[0] / (float)(B * E) - mean * mean;
    stats[n] = mean;
    stats[N + n] = rsqrtf(var + 1e-5f);
  }
}

// ---------------- BN apply + u += o + ow = o . out_w ----------------
__global__ __launch_bounds__(256) void bnapply_kernel(const float* __restrict__ gpre,
                                                      const float* __restrict__ stats,
                                                      const float* __restrict__ gamma,
                                                      const float* __restrict__ beta,
                                                      const float* __restrict__ outw,
                                                      float* __restrict__ u,
                                                      float* __restrict__ ow) {
  int tid = threadIdx.x, w = tid >> 6, l = tid & 63;
  int nw = gridDim.x * 4, wid = blockIdx.x * 4 + w;
  float wv = outw[l];
  for (int row = wid; row < BN; row += nw) {
    int n = row % N;
    float v = gpre[(size_t)row * E + l];
    float o = (v - stats[n]) * stats[N + n] * gamma[n] + beta[n];
    u[(size_t)row * E + l] += o;
    float t = o * wv;
#pragma unroll
    for (int off = 32; off > 0; off >>= 1) t += __shfl_xor(t, off);
    if (l == 0) ow[row] = t;
  }
}

// ---------------- out[b,t,n] = sum_hop sent*ow + out_b ; prev = out ----------------
__global__ __launch_bounds__(256) void outk_kernel(const float* __restrict__ sent,
                                                   const float* __restrict__ ow,
                                                   const float* __restrict__ outb,
                                                   float* __restrict__ dout,
                                                   float* __restrict__ prev,
                                                   int t) {
  int i = blockIdx.x * 256 + threadIdx.x;
  if (i < BN) {
    float v = outb[0];
#pragma unroll
    for (int h = 0; h < HOPS; ++h) v += sent[(size_t)h * BN + i] * ow[(size_t)h * BN + i];
    int b = i / N, n = i - b * N;
    dout[((size_t)b * S + t) * N + n] = v;
    prev[i] = v;
  }
}

extern "C" void kernel_launch(void* const* d_in, const int* in_sizes, int n_in,
                              void* d_out, int out_size, void* d_ws, size_t ws_size,
                              hipStream_t stream) {
  const float* hidden  = (const float*)d_in[0];
  const float* supports= (const float*)d_in[1];
  const float* memory  = (const float*)d_in[3];
  const float* nv1     = (const float*)d_in[4];
  const float* nv2     = (const float*)d_in[5];
  const float* wih     = (const float*)d_in[6];
  const float* whh     = (const float*)d_in[7];
  const float* bih     = (const float*)d_in[8];
  const float* bhh     = (const float*)d_in[9];
  const float* sent_w  = (const float*)d_in[10];
  const float* gamma   = (const float*)d_in[11];
  const float* beta    = (const float*)d_in[12];
  const float* gw      = (const float*)d_in[13];
  const float* gb      = (const float*)d_in[14];
  const float* outw    = (const float*)d_in[15];
  const float* outb    = (const float*)d_in[16];
  float* out = (float*)d_out;
  float* ws  = (float*)d_ws;

  size_t o = 0;
  float* adp  = ws + o; o += (size_t)N * N;
  float* kms  = ws + o; o += (size_t)3 * BNE;
  float* Zb   = ws + o; o += (size_t)3 * BNE;
  float* C0b  = ws + o; o += (size_t)3 * BNE;
  float* t1   = ws + o; o += (size_t)BNE;
  float* t2   = ws + o; o += (size_t)BNE;
  float* hbuf = ws + o; o += (size_t)BNE;
  float* ubuf = ws + o; o += (size_t)BNE;
  float* gpre = ws + o; o += (size_t)BNE;
  float* prev = ws + o; o += (size_t)BN;
  float* sent = ws + o; o += (size_t)3 * BN;
  float* ow   = ws + o; o += (size_t)3 * BN;
  float* stats= ws + o; o += (size_t)2 * N;

  hipMemcpyAsync(hbuf, hidden, sizeof(float) * BNE, hipMemcpyDeviceToDevice, stream);
  hipMemsetAsync(prev, 0, sizeof(float) * BN, stream);

  adp_kernel<<<N, 256, 0, stream>>>(nv1, nv2, adp);
  for (int hop = 0; hop < HOPS; ++hop)
    rowmm_kernel<<<128, 256, 0, stream>>>(memory + (size_t)hop * BNE,
                                          sent_w + (size_t)hop * E * E, nullptr,
                                          kms + (size_t)hop * BNE, 0);

  for (int hop = 0; hop < HOPS; ++hop) {
    const float* x  = memory + (size_t)(hop + 1) * BNE;
    const float* Wh = gw + (size_t)hop * 7 * E * E;
    float* Zh  = Zb + (size_t)hop * BNE;
    float* C0h = C0b + (size_t)hop * BNE;
    rowmm_kernel<<<128, 256, 0, stream>>>(x, Wh, gb + hop * E, C0h, 0);
    for (int a = 0; a < 3; ++a) {
      const float* A = (a == 0) ? supports : (a == 1) ? supports + (size_t)N * N : adp;
      bmm_kernel<<<B * NT, 256, 0, stream>>>(A, x, t1);
      rowmm_kernel<<<128, 256, 0, stream>>>(t1, Wh + (size_t)(2 * a + 1) * E * E, nullptr, Zh,
                                            (a > 0) ? 1 : 0);
      bmm_kernel<<<B * NT, 256, 0, stream>>>(A, t1, t2);
      rowmm_kernel<<<128, 256, 0, stream>>>(t2, Wh + (size_t)(2 * a + 2) * E * E, nullptr, Zh, 1);
    }
  }

  for (int t = 0; t < S; ++t) {
    gru_kernel<<<128, 256, 0, stream>>>(hbuf, prev, wih, whh, bih, bhh, ubuf);
    for (int hop = 0; hop < HOPS; ++hop) {
      attn_kernel<<<B * NT, 256, 0, stream>>>(ubuf, memory + (size_t)hop * BNE,
                                              kms + (size_t)hop * BNE,
                                              Zb + (size_t)hop * BNE,
                                              C0b + (size_t)hop * BNE,
                                              gpre, sent + (size_t)hop * BN);
      bnstats_kernel<<<N, 256, 0, stream>>>(gpre, stats);
      bnapply_kernel<<<128, 256, 0, stream>>>(gpre, stats, gamma + hop * N, beta + hop * N,
                                              outw, ubuf, ow + (size_t)hop * BN);
    }
    outk_kernel<<<(BN + 255) / 256, 256, 0, stream>>>(sent, ow, outb, out, prev, t);
  }
}

// Round 2
// 4854.041 us; speedup vs baseline: 1.5863x; 1.5863x over previous
//
#include <hip/hip_runtime.h>

constexpr int B = 32, N = 325, E = 64, S = 12, HOPS = 3;
constexpr int BN  = B * N;         // 10400
constexpr int BNE = B * N * E;     // 665600
constexpr int RT  = 16;            // rows per block (attn/bmm)
constexpr int NRT = (N + RT - 1) / RT; // 21
constexpr int EP  = E + 4;         // padded tile stride (68) -> conflict-free b128 row reads
constexpr int NP  = 328;           // padded prob/Ar stride (16B-aligned rows)
constexpr float SCALE_INV = 0.125f;

// ---------------- adp = softmax(relu(nv1 @ nv2^T)) ----------------
__global__ __launch_bounds__(256) void adp_kernel(const float* __restrict__ nv1,
                                                  const float* __restrict__ nv2,
                                                  float* __restrict__ adp) {
  int n = blockIdx.x;
  __shared__ float row[E];
  __shared__ float buf[N];
  __shared__ float red[256];
  int tid = threadIdx.x;
  if (tid < E) row[tid] = nv1[n * E + tid];
  __syncthreads();
  float lmax = -1e30f;
  for (int m = tid; m < N; m += 256) {
    const float* v2 = nv2 + (size_t)m * E;
    float s = 0.f;
#pragma unroll
    for (int e = 0; e < E; ++e) s += row[e] * v2[e];
    s = fmaxf(s, 0.f);
    buf[m] = s;
    lmax = fmaxf(lmax, s);
  }
  red[tid] = lmax;
  __syncthreads();
  for (int off = 128; off > 0; off >>= 1) {
    if (tid < off) red[tid] = fmaxf(red[tid], red[tid + off]);
    __syncthreads();
  }
  float mx = red[0];
  __syncthreads();
  float lsum = 0.f;
  for (int m = tid; m < N; m += 256) {
    float ev = expf(buf[m] - mx);
    buf[m] = ev;
    lsum += ev;
  }
  red[tid] = lsum;
  __syncthreads();
  for (int off = 128; off > 0; off >>= 1) {
    if (tid < off) red[tid] += red[tid + off];
    __syncthreads();
  }
  float inv = 1.f / red[0];
  for (int m = tid; m < N; m += 256) adp[(size_t)n * N + m] = buf[m] * inv;
}

// ---------------- out[r][e'] (+)= sum_e in[r][e] * W[e][e']  (E x E) ----------------
__global__ __launch_bounds__(256) void rowmm_kernel(const float* __restrict__ in,
                                                    const float* __restrict__ W,
                                                    const float* __restrict__ bias,
                                                    float* __restrict__ out,
                                                    int accum) {
  __shared__ float Wl[E][E + 1];
  __shared__ float rbuf[4][4][E];
  int tid = threadIdx.x, w = tid >> 6, l = tid & 63;
  for (int idx = tid; idx < E * E; idx += 256) Wl[idx >> 6][idx & 63] = W[idx];
  __syncthreads();
  float bv = bias ? bias[l] : 0.f;
  constexpr int NG = BN / 16; // 650
  for (int g = blockIdx.x; g < NG; g += gridDim.x) {
    int base = g * 16 + w * 4;
#pragma unroll
    for (int rr = 0; rr < 4; ++rr) rbuf[w][rr][l] = in[(size_t)(base + rr) * E + l];
    float acc[4];
#pragma unroll
    for (int rr = 0; rr < 4; ++rr)
      acc[rr] = accum ? out[(size_t)(base + rr) * E + l] : bv;
#pragma unroll
    for (int k = 0; k < 16; ++k) {
      float w0 = Wl[4 * k][l], w1 = Wl[4 * k + 1][l], w2 = Wl[4 * k + 2][l], w3 = Wl[4 * k + 3][l];
#pragma unroll
      for (int rr = 0; rr < 4; ++rr) {
        float4 rv = *(const float4*)&rbuf[w][rr][4 * k];
        acc[rr] += rv.x * w0 + rv.y * w1 + rv.z * w2 + rv.w * w3;
      }
    }
#pragma unroll
    for (int rr = 0; rr < 4; ++rr) out[(size_t)(base + rr) * E + l] = acc[rr];
  }
}

// ---------------- out[b,n,e] = sum_m A[n,m] * X[b,m,e]   (A shared across b) ----------------
__global__ __launch_bounds__(256) void bmm_kernel(const float* __restrict__ A,
                                                  const float* __restrict__ X,
                                                  float* __restrict__ out) {
  int b = blockIdx.x / NRT, rt = blockIdx.x % NRT;
  int n0 = rt * RT, nrows = min(RT, N - n0);
  __shared__ float Ar[RT][NP];
  __shared__ float tile[64][EP];
  int tid = threadIdx.x, w = tid >> 6, l = tid & 63;
  for (int r = w; r < RT; r += 4)
    for (int m = l; m < NP; m += 64)
      Ar[r][m] = (r < nrows && m < N) ? A[(size_t)(n0 + r) * N + m] : 0.f;
  int ti = tid >> 2, c0 = (tid & 3) * 16;
  float acc[4] = {0.f, 0.f, 0.f, 0.f};
  for (int mt = 0; mt < 6; ++mt) {
    int m0 = mt * 64, mv = min(64, N - m0);
    __syncthreads();
    {
      float4 z0, z1, z2, z3;
      if (ti < mv) {
        const float4* src = (const float4*)(X + ((size_t)b * N + m0 + ti) * E + c0);
        z0 = src[0]; z1 = src[1]; z2 = src[2]; z3 = src[3];
      } else {
        z0 = z1 = z2 = z3 = make_float4(0.f, 0.f, 0.f, 0.f);
      }
      float4* dst = (float4*)&tile[ti][c0];
      dst[0] = z0; dst[1] = z1; dst[2] = z2; dst[3] = z3;
    }
    __syncthreads();
    int jmax = (mv + 3) >> 2;
#pragma unroll 4
    for (int j = 0; j < jmax; ++j) {
      float t0 = tile[4 * j][l], t1 = tile[4 * j + 1][l];
      float t2 = tile[4 * j + 2][l], t3 = tile[4 * j + 3][l];
#pragma unroll
      for (int rr = 0; rr < 4; ++rr) {
        float4 p = *(const float4*)&Ar[w * 4 + rr][m0 + 4 * j];
        acc[rr] += p.x * t0 + p.y * t1 + p.z * t2 + p.w * t3;
      }
    }
  }
#pragma unroll
  for (int rr = 0; rr < 4; ++rr) {
    int r = w * 4 + rr;
    if (r < nrows) out[((size_t)b * N + n0 + r) * E + l] = acc[rr];
  }
}

// ---------------- fused: energy -> softmax -> score@Z + C0 ; also sentinel ----------------
__global__ __launch_bounds__(256) void attn_kernel(const float* __restrict__ u,
                                                   const float* __restrict__ key,
                                                   const float* __restrict__ kms,
                                                   const float* __restrict__ Z,
                                                   const float* __restrict__ C0,
                                                   float* __restrict__ gpre,
                                                   float* __restrict__ sent) {
  int b = blockIdx.x / NRT, rt = blockIdx.x % NRT;
  int n0 = rt * RT, nrows = min(RT, N - n0);
  __shared__ float uT[RT][E];
  __shared__ float tile[64][EP];
  __shared__ float prob[RT][NP];
  int tid = threadIdx.x, w = tid >> 6, l = tid & 63;
  for (int idx = tid; idx < nrows * E; idx += 256)
    uT[idx >> 6][idx & 63] = u[((size_t)b * N + n0) * E + idx];
  if (nrows < RT) {
    for (int idx = tid; idx < (RT - nrows) * E; idx += 256)
      uT[nrows + (idx >> 6)][idx & 63] = 0.f;
    for (int idx = tid; idx < (RT - nrows) * NP; idx += 256)
      prob[nrows + idx / NP][idx - (idx / NP) * NP] = 0.f;
  }
  __syncthreads();
  // sentinel: sent[b,n] = dot(u_row, kms_row)/8
#pragma unroll
  for (int rr = 0; rr < 4; ++rr) {
    int r = w * 4 + rr;
    if (r < nrows) {
      float v = uT[r][l] * kms[((size_t)b * N + n0 + r) * E + l];
#pragma unroll
      for (int off = 32; off > 0; off >>= 1) v += __shfl_xor(v, off);
      if (l == 0) sent[(size_t)b * N + n0 + r] = v * SCALE_INV;
    }
  }
  int ti = tid >> 2, c0 = (tid & 3) * 16;
  // ---- energy pass: lane l owns column m0+l ----
  for (int mt = 0; mt < 6; ++mt) {
    int m0 = mt * 64, mv = min(64, N - m0);
    __syncthreads();
    if (ti < mv) {
      const float4* src = (const float4*)(key + ((size_t)b * N + m0 + ti) * E + c0);
      float4 a0 = src[0], a1 = src[1], a2 = src[2], a3 = src[3];
      float4* dst = (float4*)&tile[ti][c0];
      dst[0] = a0; dst[1] = a1; dst[2] = a2; dst[3] = a3;
    }
    __syncthreads();
    if (m0 + l < N) {
      float e0 = 0.f, e1 = 0.f, e2 = 0.f, e3 = 0.f;
#pragma unroll
      for (int k = 0; k < 16; ++k) {
        float4 t  = *(const float4*)&tile[l][4 * k];
        float4 u0 = *(const float4*)&uT[w * 4 + 0][4 * k];
        float4 u1 = *(const float4*)&uT[w * 4 + 1][4 * k];
        float4 u2 = *(const float4*)&uT[w * 4 + 2][4 * k];
        float4 u3 = *(const float4*)&uT[w * 4 + 3][4 * k];
        e0 += u0.x * t.x + u0.y * t.y + u0.z * t.z + u0.w * t.w;
        e1 += u1.x * t.x + u1.y * t.y + u1.z * t.z + u1.w * t.w;
        e2 += u2.x * t.x + u2.y * t.y + u2.z * t.z + u2.w * t.w;
        e3 += u3.x * t.x + u3.y * t.y + u3.z * t.z + u3.w * t.w;
      }
      if (w * 4 + 0 < nrows) prob[w * 4 + 0][m0 + l] = e0 * SCALE_INV;
      if (w * 4 + 1 < nrows) prob[w * 4 + 1][m0 + l] = e1 * SCALE_INV;
      if (w * 4 + 2 < nrows) prob[w * 4 + 2][m0 + l] = e2 * SCALE_INV;
      if (w * 4 + 3 < nrows) prob[w * 4 + 3][m0 + l] = e3 * SCALE_INV;
    }
  }
  // ---- softmax per row (prob rows are wave-private) ----
  float rsum[4];
#pragma unroll
  for (int rr = 0; rr < 4; ++rr) {
    int r = w * 4 + rr;
    rsum[rr] = 1.f;
    if (r < nrows) {
      float v[6];
      float mx = -1e30f;
#pragma unroll
      for (int k = 0; k < 6; ++k) {
        int m = l + 64 * k;
        v[k] = (m < N) ? prob[r][m] : -1e30f;
        mx = fmaxf(mx, v[k]);
      }
#pragma unroll
      for (int off = 32; off > 0; off >>= 1) mx = fmaxf(mx, __shfl_xor(mx, off));
      float s = 0.f;
#pragma unroll
      for (int k = 0; k < 6; ++k) {
        int m = l + 64 * k;
        if (m < N) { float ev = expf(v[k] - mx); prob[r][m] = ev; s += ev; }
      }
#pragma unroll
      for (int off = 32; off > 0; off >>= 1) s += __shfl_xor(s, off);
      rsum[rr] = s;
      if (l < NP - N) prob[r][N + l] = 0.f; // zero pad cols for float4 PV reads
    }
  }
  // ---- PV pass: acc[r] = sum_m p[r][m] * Z[b,m,l] ----
  float acc[4] = {0.f, 0.f, 0.f, 0.f};
  for (int mt = 0; mt < 6; ++mt) {
    int m0 = mt * 64, mv = min(64, N - m0);
    __syncthreads();
    {
      float4 z0, z1, z2, z3;
      if (ti < mv) {
        const float4* src = (const float4*)(Z + ((size_t)b * N + m0 + ti) * E + c0);
        z0 = src[0]; z1 = src[1]; z2 = src[2]; z3 = src[3];
      } else {
        z0 = z1 = z2 = z3 = make_float4(0.f, 0.f, 0.f, 0.f);
      }
      float4* dst = (float4*)&tile[ti][c0];
      dst[0] = z0; dst[1] = z1; dst[2] = z2; dst[3] = z3;
    }
    __syncthreads();
    int jmax = (mv + 3) >> 2;
#pragma unroll 4
    for (int j = 0; j < jmax; ++j) {
      float t0 = tile[4 * j][l], t1 = tile[4 * j + 1][l];
      float t2 = tile[4 * j + 2][l], t3 = tile[4 * j + 3][l];
#pragma unroll
      for (int rr = 0; rr < 4; ++rr) {
        float4 p = *(const float4*)&prob[w * 4 + rr][m0 + 4 * j];
        acc[rr] += p.x * t0 + p.y * t1 + p.z * t2 + p.w * t3;
      }
    }
  }
#pragma unroll
  for (int rr = 0; rr < 4; ++rr) {
    int r = w * 4 + rr;
    if (r < nrows) {
      size_t gi = ((size_t)b * N + n0 + r) * E + l;
      gpre[gi] = acc[rr] / rsum[rr] + C0[gi];
    }
  }
}

// ---------------- GRU cell (OD=1 input path) ----------------
__global__ __launch_bounds__(256) void gru_kernel(float* __restrict__ h,
                                                  const float* __restrict__ prev,
                                                  const float* __restrict__ wih,
                                                  const float* __restrict__ whh,
                                                  const float* __restrict__ bih,
                                                  const float* __restrict__ bhh,
                                                  float* __restrict__ u) {
  __shared__ float W[3 * E][EP];
  __shared__ float hrow[4][E];
  int tid = threadIdx.x, w = tid >> 6, l = tid & 63;
  for (int idx = tid; idx < 3 * E * E; idx += 256) W[idx >> 6][idx & 63] = whh[idx];
  __syncthreads();
  float wi0 = wih[l], wi1 = wih[64 + l], wi2 = wih[128 + l];
  float bi0 = bih[l], bi1 = bih[64 + l], bi2 = bih[128 + l];
  float bh0 = bhh[l], bh1 = bhh[64 + l], bh2 = bhh[128 + l];
  int nw = gridDim.x * 4, wid = blockIdx.x * 4 + w;
  for (int row = wid; row < BN; row += nw) {
    float hv = h[(size_t)row * E + l];
    hrow[w][l] = hv;
    float g0 = bh0, g1 = bh1, g2 = bh2;
#pragma unroll
    for (int k = 0; k < 16; ++k) {
      float4 hh = *(const float4*)&hrow[w][4 * k];
      float4 a = *(const float4*)&W[l][4 * k];
      float4 bq = *(const float4*)&W[64 + l][4 * k];
      float4 c = *(const float4*)&W[128 + l][4 * k];
      g0 += hh.x * a.x + hh.y * a.y + hh.z * a.z + hh.w * a.w;
      g1 += hh.x * bq.x + hh.y * bq.y + hh.z * bq.z + hh.w * bq.w;
      g2 += hh.x * c.x + hh.y * c.y + hh.z * c.z + hh.w * c.w;
    }
    float pv = prev[row];
    float i0 = pv * wi0 + bi0;
    float i1 = pv * wi1 + bi1;
    float i2 = pv * wi2 + bi2;
    float r = 1.f / (1.f + expf(-(i0 + g0)));
    float z = 1.f / (1.f + expf(-(i1 + g1)));
    float nn = tanhf(i2 + r * g2);
    float hn = (1.f - z) * nn + z * hv;
    h[(size_t)row * E + l] = hn;
    u[(size_t)row * E + l] = hn;
  }
}

// ---------------- BN batch stats per node n over (B,E) ----------------
__global__ __launch_bounds__(256) void bnstats_kernel(const float* __restrict__ gpre,
                                                      float* __restrict__ stats) {
  int n = blockIdx.x;
  int tid = threadIdx.x;
  float s = 0.f, ss = 0.f;
  for (int idx = tid; idx < B * E; idx += 256) {
    int b = idx >> 6, e = idx & 63;
    float v = gpre[((size_t)b * N + n) * E + e];
    s += v; ss += v * v;
  }
  __shared__ float r1[256], r2[256];
  r1[tid] = s; r2[tid] = ss;
  __syncthreads();
  for (int off = 128; off > 0; off >>= 1) {
    if (tid < off) { r1[tid] += r1[tid + off]; r2[tid] += r2[tid + off]; }
    __syncthreads();
  }
  if (tid == 0) {
    float mean = r1[0] / (float)(B * E);
    float var = r2[0] / (float)(B * E) - mean * mean;
    stats[n] = mean;
    stats[N + n] = rsqrtf(var + 1e-5f);
  }
}

// ---------------- BN apply + u += o ; ow = o . out_w ----------------
__global__ __launch_bounds__(256) void bnapply_kernel(const float* __restrict__ gpre,
                                                      const float* __restrict__ stats,
                                                      const float* __restrict__ gamma,
                                                      const float* __restrict__ beta,
                                                      const float* __restrict__ outw,
                                                      float* __restrict__ u,
                                                      float* __restrict__ ow) {
  int tid = threadIdx.x, w = tid >> 6, l = tid & 63;
  int nw = gridDim.x * 4, wid = blockIdx.x * 4 + w;
  float wv = outw[l];
  for (int row = wid; row < BN; row += nw) {
    int n = row % N;
    float v = gpre[(size_t)row * E + l];
    float o = (v - stats[n]) * stats[N + n] * gamma[n] + beta[n];
    u[(size_t)row * E + l] += o;
    float t = o * wv;
#pragma unroll
    for (int off = 32; off > 0; off >>= 1) t += __shfl_xor(t, off);
    if (l == 0) ow[row] = t;
  }
}

// ---------------- out[b,t,n] = sum_hop sent*ow + out_b ; prev = out ----------------
__global__ __launch_bounds__(256) void outk_kernel(const float* __restrict__ sent,
                                                   const float* __restrict__ ow,
                                                   const float* __restrict__ outb,
                                                   float* __restrict__ dout,
                                                   float* __restrict__ prev,
                                                   int t) {
  int i = blockIdx.x * 256 + threadIdx.x;
  if (i < BN) {
    float v = outb[0];
#pragma unroll
    for (int h = 0; h < HOPS; ++h) v += sent[(size_t)h * BN + i] * ow[(size_t)h * BN + i];
    int b = i / N, n = i - b * N;
    dout[((size_t)b * S + t) * N + n] = v;
    prev[i] = v;
  }
}

extern "C" void kernel_launch(void* const* d_in, const int* in_sizes, int n_in,
                              void* d_out, int out_size, void* d_ws, size_t ws_size,
                              hipStream_t stream) {
  const float* hidden  = (const float*)d_in[0];
  const float* supports= (const float*)d_in[1];
  const float* memory  = (const float*)d_in[3];
  const float* nv1     = (const float*)d_in[4];
  const float* nv2     = (const float*)d_in[5];
  const float* wih     = (const float*)d_in[6];
  const float* whh     = (const float*)d_in[7];
  const float* bih     = (const float*)d_in[8];
  const float* bhh     = (const float*)d_in[9];
  const float* sent_w  = (const float*)d_in[10];
  const float* gamma   = (const float*)d_in[11];
  const float* beta    = (const float*)d_in[12];
  const float* gw      = (const float*)d_in[13];
  const float* gb      = (const float*)d_in[14];
  const float* outw    = (const float*)d_in[15];
  const float* outb    = (const float*)d_in[16];
  float* out = (float*)d_out;
  float* ws  = (float*)d_ws;

  size_t o = 0;
  float* adp  = ws + o; o += 105628;           // N*N padded to 16B multiple
  float* kms  = ws + o; o += (size_t)3 * BNE;
  float* Zb   = ws + o; o += (size_t)3 * BNE;
  float* C0b  = ws + o; o += (size_t)3 * BNE;
  float* t1   = ws + o; o += (size_t)BNE;
  float* t2   = ws + o; o += (size_t)BNE;
  float* hbuf = ws + o; o += (size_t)BNE;
  float* ubuf = ws + o; o += (size_t)BNE;
  float* gpre = ws + o; o += (size_t)BNE;
  float* prev = ws + o; o += (size_t)BN;
  float* sent = ws + o; o += (size_t)3 * BN;
  float* ow   = ws + o; o += (size_t)3 * BN;
  float* stats= ws + o; o += (size_t)2 * N;

  hipMemcpyAsync(hbuf, hidden, sizeof(float) * BNE, hipMemcpyDeviceToDevice, stream);
  hipMemsetAsync(prev, 0, sizeof(float) * BN, stream);

  adp_kernel<<<N, 256, 0, stream>>>(nv1, nv2, adp);
  for (int hop = 0; hop < HOPS; ++hop)
    rowmm_kernel<<<256, 256, 0, stream>>>(memory + (size_t)hop * BNE,
                                          sent_w + (size_t)hop * E * E, nullptr,
                                          kms + (size_t)hop * BNE, 0);

  for (int hop = 0; hop < HOPS; ++hop) {
    const float* x  = memory + (size_t)(hop + 1) * BNE;
    const float* Wh = gw + (size_t)hop * 7 * E * E;
    float* Zh  = Zb + (size_t)hop * BNE;
    float* C0h = C0b + (size_t)hop * BNE;
    rowmm_kernel<<<256, 256, 0, stream>>>(x, Wh, gb + hop * E, C0h, 0);
    for (int a = 0; a < 3; ++a) {
      const float* A = (a == 0) ? supports : (a == 1) ? supports + (size_t)N * N : adp;
      bmm_kernel<<<B * NRT, 256, 0, stream>>>(A, x, t1);
      rowmm_kernel<<<256, 256, 0, stream>>>(t1, Wh + (size_t)(2 * a + 1) * E * E, nullptr, Zh,
                                            (a > 0) ? 1 : 0);
      bmm_kernel<<<B * NRT, 256, 0, stream>>>(A, t1, t2);
      rowmm_kernel<<<256, 256, 0, stream>>>(t2, Wh + (size_t)(2 * a + 2) * E * E, nullptr, Zh, 1);
    }
  }

  for (int t = 0; t < S; ++t) {
    gru_kernel<<<512, 256, 0, stream>>>(hbuf, prev, wih, whh, bih, bhh, ubuf);
    for (int hop = 0; hop < HOPS; ++hop) {
      attn_kernel<<<B * NRT, 256, 0, stream>>>(ubuf, memory + (size_t)hop * BNE,
                                               kms + (size_t)hop * BNE,
                                               Zb + (size_t)hop * BNE,
                                               C0b + (size_t)hop * BNE,
                                               gpre, sent + (size_t)hop * BN);
      bnstats_kernel<<<N, 256, 0, stream>>>(gpre, stats);
      bnapply_kernel<<<512, 256, 0, stream>>>(gpre, stats, gamma + hop * N, beta + hop * N,
                                              outw, ubuf, ow + (size_t)hop * BN);
    }
    outk_kernel<<<(BN + 255) / 256, 256, 0, stream>>>(sent, ow, outb, out, prev, t);
  }
}

// Round 4
// 2435.715 us; speedup vs baseline: 3.1612x; 1.9929x over previous
//
#include <hip/hip_runtime.h>

constexpr int B = 32, N = 325, E = 64, S = 12, HOPS = 3;
constexpr int BN  = B * N;          // 10400
constexpr int BNE = B * N * E;      // 665600
constexpr int RT  = 16;             // rows per block (bmm)
constexpr int NRT = (N + RT - 1) / RT; // 21
constexpr int EP  = E + 4;
constexpr int NP  = 328;
constexpr int PSTR = 348;           // prob f32 stride
constexpr int PBSTR = 360;          // prob bf16 stride (11 ksteps * 32 = 352 used)
constexpr float SCALE_INV = 0.125f;

typedef __attribute__((ext_vector_type(8))) short short8v;
typedef __attribute__((ext_vector_type(4))) float f32x4;

__device__ inline short f2bf(float f) {
  unsigned x = __builtin_bit_cast(unsigned, f);
  return (short)((x + 0x7FFFu + ((x >> 16) & 1u)) >> 16);
}
__device__ inline float bf2f(short h) {
  unsigned x = ((unsigned)(unsigned short)h) << 16;
  return __builtin_bit_cast(float, x);
}

// ---------------- adp = softmax(relu(nv1 @ nv2^T)) ----------------
__global__ __launch_bounds__(256) void adp_kernel(const float* __restrict__ nv1,
                                                  const float* __restrict__ nv2,
                                                  float* __restrict__ adp) {
  int n = blockIdx.x;
  __shared__ float row[E];
  __shared__ float buf[N];
  __shared__ float red[256];
  int tid = threadIdx.x;
  if (tid < E) row[tid] = nv1[n * E + tid];
  __syncthreads();
  float lmax = -1e30f;
  for (int m = tid; m < N; m += 256) {
    const float* v2 = nv2 + (size_t)m * E;
    float s = 0.f;
#pragma unroll
    for (int e = 0; e < E; ++e) s += row[e] * v2[e];
    s = fmaxf(s, 0.f);
    buf[m] = s;
    lmax = fmaxf(lmax, s);
  }
  red[tid] = lmax;
  __syncthreads();
  for (int off = 128; off > 0; off >>= 1) {
    if (tid < off) red[tid] = fmaxf(red[tid], red[tid + off]);
    __syncthreads();
  }
  float mx = red[0];
  __syncthreads();
  float lsum = 0.f;
  for (int m = tid; m < N; m += 256) {
    float ev = expf(buf[m] - mx);
    buf[m] = ev;
    lsum += ev;
  }
  red[tid] = lsum;
  __syncthreads();
  for (int off = 128; off > 0; off >>= 1) {
    if (tid < off) red[tid] += red[tid + off];
    __syncthreads();
  }
  float inv = 1.f / red[0];
  for (int m = tid; m < N; m += 256) adp[(size_t)n * N + m] = buf[m] * inv;
}

// ---------------- rowmm body: out[r][e'] (+)= in[r][e] W[e][e'] ----------------
__device__ inline void rowmm_body(const float* __restrict__ in, const float* __restrict__ W,
                                  const float* __restrict__ bias, float* __restrict__ out,
                                  int accum, int blk, int nblk) {
  __shared__ float Wl[E][E + 1];
  __shared__ float rbuf[4][4][E];
  int tid = threadIdx.x, w = tid >> 6, l = tid & 63;
  for (int idx = tid; idx < E * E; idx += 256) Wl[idx >> 6][idx & 63] = W[idx];
  __syncthreads();
  float bv = bias ? bias[l] : 0.f;
  constexpr int NG = BN / 16; // 650
  for (int g = blk; g < NG; g += nblk) {
    int base = g * 16 + w * 4;
#pragma unroll
    for (int rr = 0; rr < 4; ++rr) rbuf[w][rr][l] = in[(size_t)(base + rr) * E + l];
    float acc[4];
#pragma unroll
    for (int rr = 0; rr < 4; ++rr)
      acc[rr] = accum ? out[(size_t)(base + rr) * E + l] : bv;
#pragma unroll
    for (int k = 0; k < 16; ++k) {
      float w0 = Wl[4 * k][l], w1 = Wl[4 * k + 1][l], w2 = Wl[4 * k + 2][l], w3 = Wl[4 * k + 3][l];
#pragma unroll
      for (int rr = 0; rr < 4; ++rr) {
        float4 rv = *(const float4*)&rbuf[w][rr][4 * k];
        acc[rr] += rv.x * w0 + rv.y * w1 + rv.z * w2 + rv.w * w3;
      }
    }
#pragma unroll
    for (int rr = 0; rr < 4; ++rr) out[(size_t)(base + rr) * E + l] = acc[rr];
  }
}

// 6 combos: c<3 -> kms[c] = memory[c] @ sent_w[c]; c>=3 -> C0[h] = memory[h+1] @ gw[h,chunk0] + gb[h]
__global__ __launch_bounds__(256) void rowmmA_kernel(const float* __restrict__ memory,
                                                     const float* __restrict__ sent_w,
                                                     const float* __restrict__ gw,
                                                     const float* __restrict__ gb,
                                                     float* __restrict__ kms,
                                                     float* __restrict__ C0) {
  int c = blockIdx.x / 112, blk = blockIdx.x % 112;
  const float *in, *W, *bias;
  float* out;
  if (c < 3) {
    in = memory + (size_t)c * BNE; W = sent_w + (size_t)c * E * E; bias = nullptr;
    out = kms + (size_t)c * BNE;
  } else {
    int h = c - 3;
    in = memory + (size_t)(h + 1) * BNE; W = gw + (size_t)h * 7 * E * E; bias = gb + h * E;
    out = C0 + (size_t)h * BNE;
  }
  rowmm_body(in, W, bias, out, 0, blk, 112);
}

// hop-batched: Z[h] (+)= t[h] @ gw[h][chunk]
__global__ __launch_bounds__(256) void rowmmZ_kernel(const float* __restrict__ tbase,
                                                     const float* __restrict__ gw,
                                                     int chunk, float* __restrict__ Zb,
                                                     int accum) {
  int h = blockIdx.x / 224, blk = blockIdx.x % 224;
  rowmm_body(tbase + (size_t)h * BNE, gw + (size_t)h * 7 * E * E + (size_t)chunk * E * E,
             nullptr, Zb + (size_t)h * BNE, accum, blk, 224);
}

// ---------------- hop-batched bmm: out[h,b,n,e] = sum_m A[n,m] X[h,b,m,e] ----------------
__global__ __launch_bounds__(256) void bmmB_kernel(const float* __restrict__ A,
                                                   const float* __restrict__ Xbase,
                                                   float* __restrict__ outBase) {
  int c = blockIdx.x / (B * NRT), rem = blockIdx.x % (B * NRT);
  int b = rem / NRT, rt = rem % NRT;
  const float* X = Xbase + (size_t)c * BNE;
  float* out = outBase + (size_t)c * BNE;
  int n0 = rt * RT, nrows = min(RT, N - n0);
  __shared__ float Ar[RT][NP];
  __shared__ float tile[64][EP];
  int tid = threadIdx.x, w = tid >> 6, l = tid & 63;
  for (int r = w; r < RT; r += 4)
    for (int m = l; m < NP; m += 64)
      Ar[r][m] = (r < nrows && m < N) ? A[(size_t)(n0 + r) * N + m] : 0.f;
  int ti = tid >> 2, c0 = (tid & 3) * 16;
  float acc[4] = {0.f, 0.f, 0.f, 0.f};
  for (int mt = 0; mt < 6; ++mt) {
    int m0 = mt * 64, mv = min(64, N - m0);
    __syncthreads();
    {
      float4 z0, z1, z2, z3;
      if (ti < mv) {
        const float4* src = (const float4*)(X + ((size_t)b * N + m0 + ti) * E + c0);
        z0 = src[0]; z1 = src[1]; z2 = src[2]; z3 = src[3];
      } else {
        z0 = z1 = z2 = z3 = make_float4(0.f, 0.f, 0.f, 0.f);
      }
      float4* dst = (float4*)&tile[ti][c0];
      dst[0] = z0; dst[1] = z1; dst[2] = z2; dst[3] = z3;
    }
    __syncthreads();
    int jmax = (mv + 3) >> 2;
#pragma unroll 4
    for (int j = 0; j < jmax; ++j) {
      float t0 = tile[4 * j][l], t1 = tile[4 * j + 1][l];
      float t2 = tile[4 * j + 2][l], t3 = tile[4 * j + 3][l];
#pragma unroll
      for (int rr = 0; rr < 4; ++rr) {
        float4 p = *(const float4*)&Ar[w * 4 + rr][m0 + 4 * j];
        acc[rr] += p.x * t0 + p.y * t1 + p.z * t2 + p.w * t3;
      }
    }
  }
#pragma unroll
  for (int rr = 0; rr < 4; ++rr) {
    int r = w * 4 + rr;
    if (r < nrows) out[((size_t)b * N + n0 + r) * E + l] = acc[rr];
  }
}

// ---------------- pack key into MFMA B-fragments (hi/lo bf16 split) ----------------
// layout: [(hop*B+b)*21+ct][ks(2)][part(2)][lane(64)][8]
__global__ __launch_bounds__(128) void kpack_kernel(const float* __restrict__ memory,
                                                    short* __restrict__ kp) {
  int idx = blockIdx.x;          // (hop*B+b)*21 + ct
  int ct = idx % 21, hb = idx / 21;
  int tid = threadIdx.x, ks = tid >> 6, l = tid & 63;
  int m = ct * 16 + (l & 15);
  int e0 = ks * 32 + (l >> 4) * 8;
  short8v hi, lo;
  if (m < N) {
    const float* p = memory + ((size_t)hb * N + m) * E + e0;
#pragma unroll
    for (int j = 0; j < 8; ++j) {
      float f = p[j];
      short h = f2bf(f);
      hi[j] = h;
      lo[j] = f2bf(f - bf2f(h));
    }
  } else {
#pragma unroll
    for (int j = 0; j < 8; ++j) { hi[j] = 0; lo[j] = 0; }
  }
  size_t base = ((size_t)idx * 2 + ks) * 1024 + (size_t)l * 8;
  *(short8v*)(kp + base) = hi;
  *(short8v*)(kp + base + 512) = lo;
}

// ---------------- pack Z into MFMA B-fragments (hi/lo bf16 split) ----------------
// layout: [(hop*B+b)*4+et][ks(11)][part(2)][lane(64)][8]
__global__ __launch_bounds__(64) void zpack_kernel(const float* __restrict__ Zb,
                                                   short* __restrict__ zp) {
  int idx = blockIdx.x;          // (hop*B+b)*4 + et
  int et = idx & 3, hb = idx >> 2;
  int l = threadIdx.x;
  int e = et * 16 + (l & 15);
  int mbase = (l >> 4) * 8;
  const float* Zp = Zb + (size_t)hb * N * E;
  for (int ks = 0; ks < 11; ++ks) {
    short8v hi, lo;
#pragma unroll
    for (int j = 0; j < 8; ++j) {
      int m = ks * 32 + mbase + j;
      float f = (m < N) ? Zp[(size_t)m * E + e] : 0.f;
      short h = f2bf(f);
      hi[j] = h;
      lo[j] = f2bf(f - bf2f(h));
    }
    size_t base = ((size_t)idx * 11 + ks) * 1024 + (size_t)l * 8;
    *(short8v*)(zp + base) = hi;
    *(short8v*)(zp + base + 512) = lo;
  }
}

// ---------------- fused attn: [bnapply(prev hop)] + sentinel + energy(MFMA) + softmax
//                  + PV(MFMA, hi/lo Z) + C0 + stats partials ----------------
__global__ __launch_bounds__(256) void attn_kernel(
    const float* __restrict__ uPrev, const float* __restrict__ gprePrev,
    const float* __restrict__ statsPrev, const float* __restrict__ gammaPrev,
    const float* __restrict__ betaPrev, const float* __restrict__ outw,
    float* __restrict__ uOut, float* __restrict__ owPrev,
    const float* __restrict__ kms, const short* __restrict__ kp,
    const short* __restrict__ zp, const float* __restrict__ C0,
    float* __restrict__ gpre, float* __restrict__ statsCur,
    float* __restrict__ sent) {
  int b = blockIdx.x / 11, rt = blockIdx.x % 11;
  int n0 = rt * 32, nrows = min(32, N - n0);
  int tid = threadIdx.x, w = tid >> 6, l = tid & 63;
  __shared__ float uT[32][68];
  __shared__ float prob[32][PSTR];
  __shared__ short pb[32][PBSTR];
  __shared__ float rsum[32];
  size_t rowbase = (size_t)b * N + n0;

  // prologue: u rows (+ fused bnapply of previous hop)
  for (int rr = 0; rr < 8; ++rr) {
    int r = w * 8 + rr;
    if (r < nrows) {
      size_t gi = (rowbase + r) * E + l;
      float uv;
      if (gprePrev) {
        int n = n0 + r;
        float m = statsPrev[n] * (1.f / 2048.f);
        float var = statsPrev[N + n] * (1.f / 2048.f) - m * m;
        float rstd = rsqrtf(var + 1e-5f);
        float o = (gprePrev[gi] - m) * rstd * gammaPrev[n] + betaPrev[n];
        uv = uPrev[gi] + o;
        if (uOut) uOut[gi] = uv;
        float tt = o * outw[l];
#pragma unroll
        for (int off = 32; off; off >>= 1) tt += __shfl_xor(tt, off);
        if (l == 0) owPrev[rowbase + r] = tt;
      } else {
        uv = uPrev[gi];
      }
      uT[r][l] = uv;
    } else if (r < 32) uT[r][l] = 0.f;
  }
  __syncthreads();
  // sentinel
  for (int rr = 0; rr < 8; ++rr) {
    int r = w * 8 + rr;
    if (r < nrows) {
      float v = uT[r][l] * kms[(rowbase + r) * E + l];
#pragma unroll
      for (int off = 32; off; off >>= 1) v += __shfl_xor(v, off);
      if (l == 0) sent[rowbase + r] = v * SCALE_INV;
    }
  }
  // A fragments (hi/lo split)
  short8v ah[2][2], al[2][2];
  {
    int arow = l & 15, ak = (l >> 4) * 8;
#pragma unroll
    for (int mt = 0; mt < 2; ++mt)
#pragma unroll
      for (int ks = 0; ks < 2; ++ks) {
        const float* p = &uT[mt * 16 + arow][ks * 32 + ak];
        short8v h, lo;
#pragma unroll
        for (int j = 0; j < 8; ++j) {
          float f = p[j];
          short hh = f2bf(f);
          h[j] = hh;
          lo[j] = f2bf(f - bf2f(hh));
        }
        ah[mt][ks] = h; al[mt][ks] = lo;
      }
  }
  // energy: 3-term hi/lo MFMA (~fp32 accuracy)
  const short8v* kpb = (const short8v*)(kp + (size_t)b * 21 * 2048);
  for (int ct = w; ct < 21; ct += 4) {
    short8v bh0 = kpb[(ct * 4 + 0) * 64 + l];
    short8v bl0 = kpb[(ct * 4 + 1) * 64 + l];
    short8v bh1 = kpb[(ct * 4 + 2) * 64 + l];
    short8v bl1 = kpb[(ct * 4 + 3) * 64 + l];
    f32x4 acc0 = {0.f, 0.f, 0.f, 0.f}, acc1 = {0.f, 0.f, 0.f, 0.f};
    acc0 = __builtin_amdgcn_mfma_f32_16x16x32_bf16(ah[0][0], bh0, acc0, 0, 0, 0);
    acc0 = __builtin_amdgcn_mfma_f32_16x16x32_bf16(ah[0][0], bl0, acc0, 0, 0, 0);
    acc0 = __builtin_amdgcn_mfma_f32_16x16x32_bf16(al[0][0], bh0, acc0, 0, 0, 0);
    acc0 = __builtin_amdgcn_mfma_f32_16x16x32_bf16(ah[0][1], bh1, acc0, 0, 0, 0);
    acc0 = __builtin_amdgcn_mfma_f32_16x16x32_bf16(ah[0][1], bl1, acc0, 0, 0, 0);
    acc0 = __builtin_amdgcn_mfma_f32_16x16x32_bf16(al[0][1], bh1, acc0, 0, 0, 0);
    acc1 = __builtin_amdgcn_mfma_f32_16x16x32_bf16(ah[1][0], bh0, acc1, 0, 0, 0);
    acc1 = __builtin_amdgcn_mfma_f32_16x16x32_bf16(ah[1][0], bl0, acc1, 0, 0, 0);
    acc1 = __builtin_amdgcn_mfma_f32_16x16x32_bf16(al[1][0], bh0, acc1, 0, 0, 0);
    acc1 = __builtin_amdgcn_mfma_f32_16x16x32_bf16(ah[1][1], bh1, acc1, 0, 0, 0);
    acc1 = __builtin_amdgcn_mfma_f32_16x16x32_bf16(ah[1][1], bl1, acc1, 0, 0, 0);
    acc1 = __builtin_amdgcn_mfma_f32_16x16x32_bf16(al[1][1], bh1, acc1, 0, 0, 0);
    int col = ct * 16 + (l & 15), r0 = (l >> 4) * 4;
#pragma unroll
    for (int r = 0; r < 4; ++r) {
      prob[r0 + r][col] = acc0[r] * SCALE_INV;
      prob[16 + r0 + r][col] = acc1[r] * SCALE_INV;
    }
  }
  __syncthreads();
  // softmax (rows wave-private); denominator = sum of bf16-ROUNDED probs
  for (int rr = 0; rr < 8; ++rr) {
    int r = w * 8 + rr;
    if (r < nrows) {
      float v[6], mx = -1e30f;
#pragma unroll
      for (int k = 0; k < 6; ++k) {
        int m = l + 64 * k;
        v[k] = (m < N) ? prob[r][m] : -1e30f;
        mx = fmaxf(mx, v[k]);
      }
#pragma unroll
      for (int off = 32; off; off >>= 1) mx = fmaxf(mx, __shfl_xor(mx, off));
      float s = 0.f;
#pragma unroll
      for (int k = 0; k < 6; ++k) {
        int m = l + 64 * k;
        if (m < PBSTR) {
          if (m < N) {
            short pv = f2bf(expf(v[k] - mx));
            pb[r][m] = pv;
            s += bf2f(pv);
          } else {
            pb[r][m] = 0;
          }
        }
      }
#pragma unroll
      for (int off = 32; off; off >>= 1) s += __shfl_xor(s, off);
      if (l == 0) rsum[r] = s;
    }
  }
  __syncthreads();
  // PV: wave -> (mtile, etile-pair); Z hi/lo
  int mt = w >> 1, e2 = (w & 1) * 2;
  const short8v* zpb = (const short8v*)(zp + (size_t)b * 4 * 11 * 1024);
  f32x4 accA = {0.f, 0.f, 0.f, 0.f}, accB = {0.f, 0.f, 0.f, 0.f};
  {
    int arow = mt * 16 + (l & 15), ak = (l >> 4) * 8;
#pragma unroll
    for (int ks = 0; ks < 11; ++ks) {
      short8v a = *(const short8v*)&pb[arow][ks * 32 + ak];
      short8v zAh = zpb[((e2 * 11 + ks) * 2 + 0) * 64 + l];
      short8v zAl = zpb[((e2 * 11 + ks) * 2 + 1) * 64 + l];
      short8v zBh = zpb[(((e2 + 1) * 11 + ks) * 2 + 0) * 64 + l];
      short8v zBl = zpb[(((e2 + 1) * 11 + ks) * 2 + 1) * 64 + l];
      accA = __builtin_amdgcn_mfma_f32_16x16x32_bf16(a, zAh, accA, 0, 0, 0);
      accA = __builtin_amdgcn_mfma_f32_16x16x32_bf16(a, zAl, accA, 0, 0, 0);
      accB = __builtin_amdgcn_mfma_f32_16x16x32_bf16(a, zBh, accB, 0, 0, 0);
      accB = __builtin_amdgcn_mfma_f32_16x16x32_bf16(a, zBl, accB, 0, 0, 0);
    }
  }
  // epilogue: gpre = acc/rsum + C0; stash in LDS for stats
  int r0 = (l >> 4) * 4, colA = e2 * 16 + (l & 15);
#pragma unroll
  for (int r = 0; r < 4; ++r) {
    int row = mt * 16 + r0 + r;
    if (row < nrows) {
      float inv = 1.f / rsum[row];
      size_t gi = (rowbase + row) * E;
      float gA = accA[r] * inv + C0[gi + colA];
      float gB = accB[r] * inv + C0[gi + colA + 16];
      gpre[gi + colA] = gA;
      gpre[gi + colA + 16] = gB;
      prob[row][colA] = gA;
      prob[row][colA + 16] = gB;
    }
  }
  __syncthreads();
  // stats partials (sum, sumsq per node)
  for (int rr = 0; rr < 8; ++rr) {
    int r = w * 8 + rr;
    if (r < nrows) {
      float v = prob[r][l];
      float s = v, q = v * v;
#pragma unroll
      for (int off = 32; off; off >>= 1) { s += __shfl_xor(s, off); q += __shfl_xor(q, off); }
      if (l == 0) {
        atomicAdd(&statsCur[n0 + r], s);
        atomicAdd(&statsCur[N + n0 + r], q);
      }
    }
  }
}

// ---------------- GRU cell (OD=1 input path) ----------------
__global__ __launch_bounds__(256) void gru_kernel(float* __restrict__ h,
                                                  const float* __restrict__ prev,
                                                  const float* __restrict__ wih,
                                                  const float* __restrict__ whh,
                                                  const float* __restrict__ bih,
                                                  const float* __restrict__ bhh,
                                                  float* __restrict__ u) {
  __shared__ float W[3 * E][EP];
  __shared__ float hrow[4][E];
  int tid = threadIdx.x, w = tid >> 6, l = tid & 63;
  for (int idx = tid; idx < 3 * E * E; idx += 256) W[idx >> 6][idx & 63] = whh[idx];
  __syncthreads();
  float wi0 = wih[l], wi1 = wih[64 + l], wi2 = wih[128 + l];
  float bi0 = bih[l], bi1 = bih[64 + l], bi2 = bih[128 + l];
  float bh0 = bhh[l], bh1 = bhh[64 + l], bh2 = bhh[128 + l];
  int nw = gridDim.x * 4, wid = blockIdx.x * 4 + w;
  for (int row = wid; row < BN; row += nw) {
    float hv = h[(size_t)row * E + l];
    hrow[w][l] = hv;
    float g0 = bh0, g1 = bh1, g2 = bh2;
#pragma unroll
    for (int k = 0; k < 16; ++k) {
      float4 hh = *(const float4*)&hrow[w][4 * k];
      float4 a = *(const float4*)&W[l][4 * k];
      float4 bq = *(const float4*)&W[64 + l][4 * k];
      float4 c = *(const float4*)&W[128 + l][4 * k];
      g0 += hh.x * a.x + hh.y * a.y + hh.z * a.z + hh.w * a.w;
      g1 += hh.x * bq.x + hh.y * bq.y + hh.z * bq.z + hh.w * bq.w;
      g2 += hh.x * c.x + hh.y * c.y + hh.z * c.z + hh.w * c.w;
    }
    float pv = prev[row];
    float i0 = pv * wi0 + bi0;
    float i1 = pv * wi1 + bi1;
    float i2 = pv * wi2 + bi2;
    float r = 1.f / (1.f + expf(-(i0 + g0)));
    float z = 1.f / (1.f + expf(-(i1 + g1)));
    float nn = tanhf(i2 + r * g2);
    float hn = (1.f - z) * nn + z * hv;
    h[(size_t)row * E + l] = hn;
    u[(size_t)row * E + l] = hn;
  }
}

// ---------------- finish: bnapply(hop2) + ow2 + out + prev ----------------
__global__ __launch_bounds__(256) void finish_kernel(
    const float* __restrict__ gpre2, const float* __restrict__ stats2,
    const float* __restrict__ gamma2, const float* __restrict__ beta2,
    const float* __restrict__ outw, const float* __restrict__ outb,
    const float* __restrict__ sent, const float* __restrict__ ow01,
    float* __restrict__ dout, float* __restrict__ prev, int t) {
  int tid = threadIdx.x, w = tid >> 6, l = tid & 63;
  int wid = blockIdx.x * 4 + w, nw = gridDim.x * 4;
  float wv = outw[l];
  for (int row = wid; row < BN; row += nw) {
    int n = row % N;
    float m = stats2[n] * (1.f / 2048.f);
    float var = stats2[N + n] * (1.f / 2048.f) - m * m;
    float rstd = rsqrtf(var + 1e-5f);
    float o = (gpre2[(size_t)row * E + l] - m) * rstd * gamma2[n] + beta2[n];
    float tt = o * wv;
#pragma unroll
    for (int off = 32; off; off >>= 1) tt += __shfl_xor(tt, off);
    if (l == 0) {
      float v = outb[0] + sent[row] * ow01[row] + sent[BN + row] * ow01[BN + row]
              + sent[2 * BN + row] * tt;
      int b = row / N;
      dout[((size_t)b * S + t) * N + (row - b * N)] = v;
      prev[row] = v;
    }
  }
}

extern "C" void kernel_launch(void* const* d_in, const int* in_sizes, int n_in,
                              void* d_out, int out_size, void* d_ws, size_t ws_size,
                              hipStream_t stream) {
  const float* hidden   = (const float*)d_in[0];
  const float* supports = (const float*)d_in[1];
  const float* memory   = (const float*)d_in[3];
  const float* nv1      = (const float*)d_in[4];
  const float* nv2      = (const float*)d_in[5];
  const float* wih      = (const float*)d_in[6];
  const float* whh      = (const float*)d_in[7];
  const float* bih      = (const float*)d_in[8];
  const float* bhh      = (const float*)d_in[9];
  const float* sent_w   = (const float*)d_in[10];
  const float* gamma    = (const float*)d_in[11];
  const float* beta     = (const float*)d_in[12];
  const float* gw       = (const float*)d_in[13];
  const float* gb       = (const float*)d_in[14];
  const float* outw     = (const float*)d_in[15];
  const float* outb     = (const float*)d_in[16];
  float* out = (float*)d_out;
  float* ws  = (float*)d_ws;

  size_t o = 0;
  float* adp   = ws + o; o += 105632;
  float* kms   = ws + o; o += (size_t)3 * BNE;
  float* C0b   = ws + o; o += (size_t)3 * BNE;
  float* hbuf  = ws + o; o += (size_t)BNE;
  float* ubuf  = ws + o; o += (size_t)BNE;
  float* u1    = ws + o; o += (size_t)BNE;
  float* uni   = ws + o; o += (size_t)9 * BNE;  // precompute: Zb(3)+t1(3)+t2(3); steps: g0..g2
  float* Zb  = uni;
  float* t1b = uni + (size_t)3 * BNE;
  float* t2b = uni + (size_t)6 * BNE;
  float* g0 = uni, *g1 = uni + BNE, *g2 = uni + (size_t)2 * BNE;
  short* kpackS = (short*)(ws + o); o += 2064384;   // 3*B*21*2*2*512 shorts = 4,128,768 sh = 2,064,384 fl
  short* zpackS = (short*)(ws + o); o += 2162688;   // 3*B*4*11*2*512 shorts = 4,325,376 sh = 2,162,688 fl
  float* prev   = ws + o; o += BN;
  float* sentb  = ws + o; o += (size_t)3 * BN;
  float* owb    = ws + o; o += (size_t)2 * BN;
  float* statsb = ws + o; o += (size_t)36 * 650;

  hipMemcpyAsync(hbuf, hidden, sizeof(float) * BNE, hipMemcpyDeviceToDevice, stream);
  hipMemsetAsync(prev, 0, sizeof(float) * BN, stream);
  hipMemsetAsync(statsb, 0, sizeof(float) * 36 * 650, stream);

  adp_kernel<<<N, 256, 0, stream>>>(nv1, nv2, adp);
  rowmmA_kernel<<<672, 256, 0, stream>>>(memory, sent_w, gw, gb, kms, C0b);
  kpack_kernel<<<3 * B * 21, 128, 0, stream>>>(memory, kpackS);

  for (int a = 0; a < 3; ++a) {
    const float* A = (a == 0) ? supports : (a == 1) ? supports + (size_t)N * N : adp;
    bmmB_kernel<<<3 * B * NRT, 256, 0, stream>>>(A, memory + BNE, t1b);
    rowmmZ_kernel<<<672, 256, 0, stream>>>(t1b, gw, 2 * a + 1, Zb, (a > 0) ? 1 : 0);
    bmmB_kernel<<<3 * B * NRT, 256, 0, stream>>>(A, t1b, t2b);
    rowmmZ_kernel<<<672, 256, 0, stream>>>(t2b, gw, 2 * a + 2, Zb, 1);
  }
  zpack_kernel<<<3 * B * 4, 64, 0, stream>>>(Zb, zpackS);

  for (int t = 0; t < S; ++t) {
    float* st0 = statsb + (size_t)(t * 3 + 0) * 650;
    float* st1 = statsb + (size_t)(t * 3 + 1) * 650;
    float* st2 = statsb + (size_t)(t * 3 + 2) * 650;
    gru_kernel<<<512, 256, 0, stream>>>(hbuf, prev, wih, whh, bih, bhh, ubuf);
    attn_kernel<<<B * 11, 256, 0, stream>>>(
        ubuf, nullptr, nullptr, nullptr, nullptr, outw, nullptr, nullptr,
        kms, kpackS, zpackS, C0b, g0, st0, sentb);
    attn_kernel<<<B * 11, 256, 0, stream>>>(
        ubuf, g0, st0, gamma, beta, outw, u1, owb,
        kms + BNE, kpackS + (size_t)B * 21 * 2048, zpackS + (size_t)B * 4 * 11 * 1024,
        C0b + BNE, g1, st1, sentb + BN);
    attn_kernel<<<B * 11, 256, 0, stream>>>(
        u1, g1, st1, gamma + N, beta + N, outw, nullptr, owb + BN,
        kms + (size_t)2 * BNE, kpackS + (size_t)2 * B * 21 * 2048,
        zpackS + (size_t)2 * B * 4 * 11 * 1024,
        C0b + (size_t)2 * BNE, g2, st2, sentb + (size_t)2 * BN);
    finish_kernel<<<256, 256, 0, stream>>>(g2, st2, gamma + 2 * N, beta + 2 * N,
                                           outw, outb, sentb, owb, out, prev, t);
  }
}

// Round 6
// 2304.170 us; speedup vs baseline: 3.3417x; 1.0571x over previous
//
#include <hip/hip_runtime.h>

constexpr int B = 32, N = 325, E = 64, S = 12, HOPS = 3;
constexpr int BN  = B * N;          // 10400
constexpr int BNE = B * N * E;      // 665600
constexpr int RT  = 16;             // rows per block (bmm)
constexpr int NRT = (N + RT - 1) / RT; // 21
constexpr int EP  = E + 4;
constexpr int NP  = 328;
constexpr int PBSTR = 360;          // prob bf16 stride (11 ksteps * 32 = 352 used)
constexpr float SCALE_INV = 0.125f;

typedef __attribute__((ext_vector_type(8))) short short8v;
typedef __attribute__((ext_vector_type(4))) float f32x4;

__device__ inline short f2bf(float f) {
  unsigned x = __builtin_bit_cast(unsigned, f);
  return (short)((x + 0x7FFFu + ((x >> 16) & 1u)) >> 16);
}
__device__ inline float bf2f(short h) {
  unsigned x = ((unsigned)(unsigned short)h) << 16;
  return __builtin_bit_cast(float, x);
}

// ---------------- adp = softmax(relu(nv1 @ nv2^T)) ----------------
__global__ __launch_bounds__(256) void adp_kernel(const float* __restrict__ nv1,
                                                  const float* __restrict__ nv2,
                                                  float* __restrict__ adp) {
  int n = blockIdx.x;
  __shared__ float row[E];
  __shared__ float buf[N];
  __shared__ float red[256];
  int tid = threadIdx.x;
  if (tid < E) row[tid] = nv1[n * E + tid];
  __syncthreads();
  float lmax = -1e30f;
  for (int m = tid; m < N; m += 256) {
    const float* v2 = nv2 + (size_t)m * E;
    float s = 0.f;
#pragma unroll
    for (int e = 0; e < E; ++e) s += row[e] * v2[e];
    s = fmaxf(s, 0.f);
    buf[m] = s;
    lmax = fmaxf(lmax, s);
  }
  red[tid] = lmax;
  __syncthreads();
  for (int off = 128; off > 0; off >>= 1) {
    if (tid < off) red[tid] = fmaxf(red[tid], red[tid + off]);
    __syncthreads();
  }
  float mx = red[0];
  __syncthreads();
  float lsum = 0.f;
  for (int m = tid; m < N; m += 256) {
    float ev = expf(buf[m] - mx);
    buf[m] = ev;
    lsum += ev;
  }
  red[tid] = lsum;
  __syncthreads();
  for (int off = 128; off > 0; off >>= 1) {
    if (tid < off) red[tid] += red[tid + off];
    __syncthreads();
  }
  float inv = 1.f / red[0];
  for (int m = tid; m < N; m += 256) adp[(size_t)n * N + m] = buf[m] * inv;
}

// ---------------- rowmm body: out[r][e'] (+)= in[r][e] W[e][e'] ----------------
__device__ inline void rowmm_body(const float* __restrict__ in, const float* __restrict__ W,
                                  const float* __restrict__ bias, float* __restrict__ out,
                                  int accum, int blk, int nblk) {
  __shared__ float Wl[E][E + 1];
  __shared__ float rbuf[4][4][E];
  int tid = threadIdx.x, w = tid >> 6, l = tid & 63;
  for (int idx = tid; idx < E * E; idx += 256) Wl[idx >> 6][idx & 63] = W[idx];
  __syncthreads();
  float bv = bias ? bias[l] : 0.f;
  constexpr int NG = BN / 16; // 650
  for (int g = blk; g < NG; g += nblk) {
    int base = g * 16 + w * 4;
#pragma unroll
    for (int rr = 0; rr < 4; ++rr) rbuf[w][rr][l] = in[(size_t)(base + rr) * E + l];
    float acc[4];
#pragma unroll
    for (int rr = 0; rr < 4; ++rr)
      acc[rr] = accum ? out[(size_t)(base + rr) * E + l] : bv;
#pragma unroll
    for (int k = 0; k < 16; ++k) {
      float w0 = Wl[4 * k][l], w1 = Wl[4 * k + 1][l], w2 = Wl[4 * k + 2][l], w3 = Wl[4 * k + 3][l];
#pragma unroll
      for (int rr = 0; rr < 4; ++rr) {
        float4 rv = *(const float4*)&rbuf[w][rr][4 * k];
        acc[rr] += rv.x * w0 + rv.y * w1 + rv.z * w2 + rv.w * w3;
      }
    }
#pragma unroll
    for (int rr = 0; rr < 4; ++rr) out[(size_t)(base + rr) * E + l] = acc[rr];
  }
}

// 6 combos: c<3 -> kms[c]; c>=3 -> C0[h]
__global__ __launch_bounds__(256) void rowmmA_kernel(const float* __restrict__ memory,
                                                     const float* __restrict__ sent_w,
                                                     const float* __restrict__ gw,
                                                     const float* __restrict__ gb,
                                                     float* __restrict__ kms,
                                                     float* __restrict__ C0) {
  int c = blockIdx.x / 112, blk = blockIdx.x % 112;
  const float *in, *W, *bias;
  float* out;
  if (c < 3) {
    in = memory + (size_t)c * BNE; W = sent_w + (size_t)c * E * E; bias = nullptr;
    out = kms + (size_t)c * BNE;
  } else {
    int h = c - 3;
    in = memory + (size_t)(h + 1) * BNE; W = gw + (size_t)h * 7 * E * E; bias = gb + h * E;
    out = C0 + (size_t)h * BNE;
  }
  rowmm_body(in, W, bias, out, 0, blk, 112);
}

__global__ __launch_bounds__(256) void rowmmZ_kernel(const float* __restrict__ tbase,
                                                     const float* __restrict__ gw,
                                                     int chunk, float* __restrict__ Zb,
                                                     int accum) {
  int h = blockIdx.x / 224, blk = blockIdx.x % 224;
  rowmm_body(tbase + (size_t)h * BNE, gw + (size_t)h * 7 * E * E + (size_t)chunk * E * E,
             nullptr, Zb + (size_t)h * BNE, accum, blk, 224);
}

// ---------------- hop-batched bmm: out[h,b,n,e] = sum_m A[n,m] X[h,b,m,e] ----------------
__global__ __launch_bounds__(256) void bmmB_kernel(const float* __restrict__ A,
                                                   const float* __restrict__ Xbase,
                                                   float* __restrict__ outBase) {
  int c = blockIdx.x / (B * NRT), rem = blockIdx.x % (B * NRT);
  int b = rem / NRT, rt = rem % NRT;
  const float* X = Xbase + (size_t)c * BNE;
  float* out = outBase + (size_t)c * BNE;
  int n0 = rt * RT, nrows = min(RT, N - n0);
  __shared__ float Ar[RT][NP];
  __shared__ float tile[64][EP];
  int tid = threadIdx.x, w = tid >> 6, l = tid & 63;
  for (int r = w; r < RT; r += 4)
    for (int m = l; m < NP; m += 64)
      Ar[r][m] = (r < nrows && m < N) ? A[(size_t)(n0 + r) * N + m] : 0.f;
  int ti = tid >> 2, c0 = (tid & 3) * 16;
  float acc[4] = {0.f, 0.f, 0.f, 0.f};
  for (int mt = 0; mt < 6; ++mt) {
    int m0 = mt * 64, mv = min(64, N - m0);
    __syncthreads();
    {
      float4 z0, z1, z2, z3;
      if (ti < mv) {
        const float4* src = (const float4*)(X + ((size_t)b * N + m0 + ti) * E + c0);
        z0 = src[0]; z1 = src[1]; z2 = src[2]; z3 = src[3];
      } else {
        z0 = z1 = z2 = z3 = make_float4(0.f, 0.f, 0.f, 0.f);
      }
      float4* dst = (float4*)&tile[ti][c0];
      dst[0] = z0; dst[1] = z1; dst[2] = z2; dst[3] = z3;
    }
    __syncthreads();
    int jmax = (mv + 3) >> 2;
#pragma unroll 4
    for (int j = 0; j < jmax; ++j) {
      float t0 = tile[4 * j][l], t1 = tile[4 * j + 1][l];
      float t2 = tile[4 * j + 2][l], t3 = tile[4 * j + 3][l];
#pragma unroll
      for (int rr = 0; rr < 4; ++rr) {
        float4 p = *(const float4*)&Ar[w * 4 + rr][m0 + 4 * j];
        acc[rr] += p.x * t0 + p.y * t1 + p.z * t2 + p.w * t3;
      }
    }
  }
#pragma unroll
  for (int rr = 0; rr < 4; ++rr) {
    int r = w * 4 + rr;
    if (r < nrows) out[((size_t)b * N + n0 + r) * E + l] = acc[rr];
  }
}

// ---------------- pack key into MFMA B-fragments (hi/lo bf16 split) ----------------
__global__ __launch_bounds__(128) void kpack_kernel(const float* __restrict__ memory,
                                                    short* __restrict__ kp) {
  int idx = blockIdx.x;          // (hop*B+b)*21 + ct
  int ct = idx % 21, hb = idx / 21;
  int tid = threadIdx.x, ks = tid >> 6, l = tid & 63;
  int m = ct * 16 + (l & 15);
  int e0 = ks * 32 + (l >> 4) * 8;
  short8v hi, lo;
  if (m < N) {
    const float* p = memory + ((size_t)hb * N + m) * E + e0;
#pragma unroll
    for (int j = 0; j < 8; ++j) {
      float f = p[j];
      short h = f2bf(f);
      hi[j] = h;
      lo[j] = f2bf(f - bf2f(h));
    }
  } else {
#pragma unroll
    for (int j = 0; j < 8; ++j) { hi[j] = 0; lo[j] = 0; }
  }
  size_t base = ((size_t)idx * 2 + ks) * 1024 + (size_t)l * 8;
  *(short8v*)(kp + base) = hi;
  *(short8v*)(kp + base + 512) = lo;
}

// ---------------- pack Z into MFMA B-fragments (hi/lo bf16 split) ----------------
__global__ __launch_bounds__(64) void zpack_kernel(const float* __restrict__ Zb,
                                                   short* __restrict__ zp) {
  int idx = blockIdx.x;          // (hop*B+b)*4 + et
  int et = idx & 3, hb = idx >> 2;
  int l = threadIdx.x;
  int e = et * 16 + (l & 15);
  int mbase = (l >> 4) * 8;
  const float* Zp = Zb + (size_t)hb * N * E;
  for (int ks = 0; ks < 11; ++ks) {
    short8v hi, lo;
#pragma unroll
    for (int j = 0; j < 8; ++j) {
      int m = ks * 32 + mbase + j;
      float f = (m < N) ? Zp[(size_t)m * E + e] : 0.f;
      short h = f2bf(f);
      hi[j] = h;
      lo[j] = f2bf(f - bf2f(h));
    }
    size_t base = ((size_t)idx * 11 + ks) * 1024 + (size_t)l * 8;
    *(short8v*)(zp + base) = hi;
    *(short8v*)(zp + base + 512) = lo;
  }
}

// ---------------- fused attn (512 thr): [bnapply prev] + sentinel + energy MFMA +
//                  in-register softmax + PV MFMA + C0 + stats ----------------
__global__ __launch_bounds__(512) void attn_kernel(
    const float* __restrict__ uPrev, const float* __restrict__ gprePrev,
    const float* __restrict__ statsPrev, const float* __restrict__ gammaPrev,
    const float* __restrict__ betaPrev, const float* __restrict__ outw,
    float* __restrict__ uOut, float* __restrict__ owPrev,
    const float* __restrict__ kms, const short* __restrict__ kp,
    const short* __restrict__ zp, const float* __restrict__ C0,
    float* __restrict__ gpre, float* __restrict__ statsCur,
    float* __restrict__ sent) {
  int b = blockIdx.x / 11, rt = blockIdx.x % 11;
  int n0 = rt * 32, nrows = min(32, N - n0);
  int tid = threadIdx.x, w = tid >> 6, l = tid & 63;
  __shared__ float uT[32][68];
  __shared__ short pb[32][PBSTR];
  __shared__ float rowred[32][8];
  __shared__ float rmax[32];
  __shared__ float rsinv[32];
  size_t rowbase = (size_t)b * N + n0;
  int g = l >> 4;

  // zero pb pad cols [336, PBSTR)
  for (int idx = tid; idx < 32 * (PBSTR - 336); idx += 512) {
    int r = idx / (PBSTR - 336), c = idx - r * (PBSTR - 336);
    pb[r][336 + c] = 0;
  }
  // prologue: u rows (+ fused bnapply of previous hop); 4 rows/wave
#pragma unroll
  for (int rr = 0; rr < 4; ++rr) {
    int r = w * 4 + rr;
    if (r < nrows) {
      size_t gi = (rowbase + r) * E + l;
      float uv;
      if (gprePrev) {
        int n = n0 + r;
        float m = statsPrev[n] * (1.f / 2048.f);
        float var = statsPrev[N + n] * (1.f / 2048.f) - m * m;
        float rstd = rsqrtf(var + 1e-5f);
        float o = (gprePrev[gi] - m) * rstd * gammaPrev[n] + betaPrev[n];
        uv = uPrev[gi] + o;
        if (uOut) uOut[gi] = uv;
        float tt = o * outw[l];
#pragma unroll
        for (int off = 32; off; off >>= 1) tt += __shfl_xor(tt, off);
        if (l == 0) owPrev[rowbase + r] = tt;
      } else {
        uv = uPrev[gi];
      }
      uT[r][l] = uv;
    } else {
      uT[r][l] = 0.f;
    }
  }
  __syncthreads();
  // sentinel
#pragma unroll
  for (int rr = 0; rr < 4; ++rr) {
    int r = w * 4 + rr;
    if (r < nrows) {
      float v = uT[r][l] * kms[(rowbase + r) * E + l];
#pragma unroll
      for (int off = 32; off; off >>= 1) v += __shfl_xor(v, off);
      if (l == 0) sent[rowbase + r] = v * SCALE_INV;
    }
  }
  // A fragments (hi/lo split)
  short8v ah[2][2], al[2][2];
  {
    int arow = l & 15, ak = g * 8;
#pragma unroll
    for (int mt = 0; mt < 2; ++mt)
#pragma unroll
      for (int ks = 0; ks < 2; ++ks) {
        const float* p = &uT[mt * 16 + arow][ks * 32 + ak];
        short8v h, lo;
#pragma unroll
        for (int j = 0; j < 8; ++j) {
          float f = p[j];
          short hh = f2bf(f);
          h[j] = hh;
          lo[j] = f2bf(f - bf2f(hh));
        }
        ah[mt][ks] = h; al[mt][ks] = lo;
      }
  }
  // energy: wave handles ct = w, w+8, w+16 (3-term hi/lo MFMA)
  const short8v* kpb = (const short8v*)(kp + (size_t)b * 21 * 2048);
  f32x4 acc0[3], acc1[3];
#pragma unroll
  for (int i = 0; i < 3; ++i) {
    acc0[i] = (f32x4){0.f, 0.f, 0.f, 0.f};
    acc1[i] = (f32x4){0.f, 0.f, 0.f, 0.f};
    int ct = w + 8 * i;
    if (ct < 21) {
      short8v bh0 = kpb[(ct * 4 + 0) * 64 + l];
      short8v bl0 = kpb[(ct * 4 + 1) * 64 + l];
      short8v bh1 = kpb[(ct * 4 + 2) * 64 + l];
      short8v bl1 = kpb[(ct * 4 + 3) * 64 + l];
      f32x4 a0 = acc0[i], a1 = acc1[i];
      a0 = __builtin_amdgcn_mfma_f32_16x16x32_bf16(ah[0][0], bh0, a0, 0, 0, 0);
      a0 = __builtin_amdgcn_mfma_f32_16x16x32_bf16(ah[0][0], bl0, a0, 0, 0, 0);
      a0 = __builtin_amdgcn_mfma_f32_16x16x32_bf16(al[0][0], bh0, a0, 0, 0, 0);
      a0 = __builtin_amdgcn_mfma_f32_16x16x32_bf16(ah[0][1], bh1, a0, 0, 0, 0);
      a0 = __builtin_amdgcn_mfma_f32_16x16x32_bf16(ah[0][1], bl1, a0, 0, 0, 0);
      a0 = __builtin_amdgcn_mfma_f32_16x16x32_bf16(al[0][1], bh1, a0, 0, 0, 0);
      a1 = __builtin_amdgcn_mfma_f32_16x16x32_bf16(ah[1][0], bh0, a1, 0, 0, 0);
      a1 = __builtin_amdgcn_mfma_f32_16x16x32_bf16(ah[1][0], bl0, a1, 0, 0, 0);
      a1 = __builtin_amdgcn_mfma_f32_16x16x32_bf16(al[1][0], bh0, a1, 0, 0, 0);
      a1 = __builtin_amdgcn_mfma_f32_16x16x32_bf16(ah[1][1], bh1, a1, 0, 0, 0);
      a1 = __builtin_amdgcn_mfma_f32_16x16x32_bf16(ah[1][1], bl1, a1, 0, 0, 0);
      a1 = __builtin_amdgcn_mfma_f32_16x16x32_bf16(al[1][1], bh1, a1, 0, 0, 0);
      acc0[i] = a0; acc1[i] = a1;
    }
  }
  // per-row partial max (raw acc; softmax is shift-invariant so padded zeros are safe)
  {
    float m0[4], m1[4];
#pragma unroll
    for (int r = 0; r < 4; ++r) {
      float a = -1e30f, c = -1e30f;
#pragma unroll
      for (int i = 0; i < 3; ++i)
        if (w + 8 * i < 21) { a = fmaxf(a, acc0[i][r]); c = fmaxf(c, acc1[i][r]); }
#pragma unroll
      for (int off = 1; off < 16; off <<= 1) {
        a = fmaxf(a, __shfl_xor(a, off));
        c = fmaxf(c, __shfl_xor(c, off));
      }
      m0[r] = a; m1[r] = c;
    }
    if ((l & 15) == 0) {
#pragma unroll
      for (int r = 0; r < 4; ++r) {
        rowred[g * 4 + r][w] = m0[r];
        rowred[16 + g * 4 + r][w] = m1[r];
      }
    }
  }
  __syncthreads();
  if (tid < 32) {
    float a = rowred[tid][0];
#pragma unroll
    for (int j = 1; j < 8; ++j) a = fmaxf(a, rowred[tid][j]);
    rmax[tid] = a;
  }
  __syncthreads();
  // exp + bf16 round + partial sums (denominator = sum of bf16-rounded probs)
  {
    float mx0[4], mx1[4], s0[4], s1[4];
#pragma unroll
    for (int r = 0; r < 4; ++r) {
      mx0[r] = rmax[g * 4 + r]; mx1[r] = rmax[16 + g * 4 + r];
      s0[r] = 0.f; s1[r] = 0.f;
    }
#pragma unroll
    for (int i = 0; i < 3; ++i) {
      int ct = w + 8 * i;
      if (ct < 21) {
        int col = ct * 16 + (l & 15);
        bool valid = col < N;
#pragma unroll
        for (int r = 0; r < 4; ++r) {
          short pv0 = 0, pv1 = 0;
          if (valid) {
            pv0 = f2bf(expf((acc0[i][r] - mx0[r]) * SCALE_INV));
            pv1 = f2bf(expf((acc1[i][r] - mx1[r]) * SCALE_INV));
            s0[r] += bf2f(pv0);
            s1[r] += bf2f(pv1);
          }
          pb[g * 4 + r][col] = pv0;
          pb[16 + g * 4 + r][col] = pv1;
        }
      }
    }
#pragma unroll
    for (int r = 0; r < 4; ++r) {
#pragma unroll
      for (int off = 1; off < 16; off <<= 1) {
        s0[r] += __shfl_xor(s0[r], off);
        s1[r] += __shfl_xor(s1[r], off);
      }
    }
    if ((l & 15) == 0) {
#pragma unroll
      for (int r = 0; r < 4; ++r) {
        rowred[g * 4 + r][w] = s0[r];
        rowred[16 + g * 4 + r][w] = s1[r];
      }
    }
  }
  __syncthreads();
  if (tid < 32) {
    float s = 0.f;
#pragma unroll
    for (int j = 0; j < 8; ++j) s += rowred[tid][j];
    rsinv[tid] = 1.f / s;
  }
  __syncthreads();
  // PV: wave -> (mt = w>>2, et = w&3); Z hi/lo
  int mt = w >> 2, et = w & 3;
  const short8v* zpb = (const short8v*)(zp + (size_t)b * 4 * 11 * 1024);
  f32x4 acc = {0.f, 0.f, 0.f, 0.f};
  {
    int arow = mt * 16 + (l & 15), ak = g * 8;
#pragma unroll
    for (int ks = 0; ks < 11; ++ks) {
      short8v a = *(const short8v*)&pb[arow][ks * 32 + ak];
      short8v zh = zpb[((et * 11 + ks) * 2 + 0) * 64 + l];
      short8v zl = zpb[((et * 11 + ks) * 2 + 1) * 64 + l];
      acc = __builtin_amdgcn_mfma_f32_16x16x32_bf16(a, zh, acc, 0, 0, 0);
      acc = __builtin_amdgcn_mfma_f32_16x16x32_bf16(a, zl, acc, 0, 0, 0);
    }
  }
  // epilogue: gpre = acc/rsum + C0; stats via 16-lane reduce + atomics
  int colA = et * 16 + (l & 15);
#pragma unroll
  for (int r = 0; r < 4; ++r) {
    int row = mt * 16 + g * 4 + r;
    float sval = 0.f, qval = 0.f;
    if (row < nrows) {
      size_t gi = (rowbase + row) * E + colA;
      float gA = acc[r] * rsinv[row] + C0[gi];
      gpre[gi] = gA;
      sval = gA; qval = gA * gA;
    }
#pragma unroll
    for (int off = 1; off < 16; off <<= 1) {
      sval += __shfl_xor(sval, off);
      qval += __shfl_xor(qval, off);
    }
    if ((l & 15) == 0 && row < nrows) {
      atomicAdd(&statsCur[n0 + row], sval);
      atomicAdd(&statsCur[N + n0 + row], qval);
    }
  }
}

// ---------------- GRU cell with fused finish of previous step ----------------
__global__ __launch_bounds__(256) void gru_kernel(
    float* __restrict__ h,
    const float* __restrict__ gpre2, const float* __restrict__ stats2,
    const float* __restrict__ gamma2, const float* __restrict__ beta2,
    const float* __restrict__ outw, const float* __restrict__ outb,
    const float* __restrict__ sentb, const float* __restrict__ owb,
    float* __restrict__ dout, int tprev,
    const float* __restrict__ wih, const float* __restrict__ whh,
    const float* __restrict__ bih, const float* __restrict__ bhh,
    float* __restrict__ u) {
  __shared__ float W[3 * E][EP];
  __shared__ float hrow[4][E];
  int tid = threadIdx.x, w = tid >> 6, l = tid & 63;
  for (int idx = tid; idx < 3 * E * E; idx += 256) W[idx >> 6][idx & 63] = whh[idx];
  __syncthreads();
  float wi0 = wih[l], wi1 = wih[64 + l], wi2 = wih[128 + l];
  float bi0 = bih[l], bi1 = bih[64 + l], bi2 = bih[128 + l];
  float bh0 = bhh[l], bh1 = bhh[64 + l], bh2 = bhh[128 + l];
  float wv = outw[l];
  float ob = outb[0];
  int nw = gridDim.x * 4, wid = blockIdx.x * 4 + w;
  for (int row = wid; row < BN; row += nw) {
    float hv = h[(size_t)row * E + l];
    hrow[w][l] = hv;
    float pv = 0.f;
    if (gpre2) {  // fused finish of step tprev
      int n = row % N;
      float m = stats2[n] * (1.f / 2048.f);
      float var = stats2[N + n] * (1.f / 2048.f) - m * m;
      float rstd = rsqrtf(var + 1e-5f);
      float o = (gpre2[(size_t)row * E + l] - m) * rstd * gamma2[n] + beta2[n];
      float tt = o * wv;
#pragma unroll
      for (int off = 32; off; off >>= 1) tt += __shfl_xor(tt, off);
      float v = ob + sentb[row] * owb[row] + sentb[BN + row] * owb[BN + row]
              + sentb[2 * BN + row] * tt;
      pv = v;
      if (l == 0) {
        int bb = row / N;
        dout[((size_t)bb * S + tprev) * N + (row - bb * N)] = v;
      }
    }
    float g0 = bh0, g1 = bh1, g2 = bh2;
#pragma unroll
    for (int k = 0; k < 16; ++k) {
      float4 hh = *(const float4*)&hrow[w][4 * k];
      float4 a = *(const float4*)&W[l][4 * k];
      float4 bq = *(const float4*)&W[64 + l][4 * k];
      float4 c = *(const float4*)&W[128 + l][4 * k];
      g0 += hh.x * a.x + hh.y * a.y + hh.z * a.z + hh.w * a.w;
      g1 += hh.x * bq.x + hh.y * bq.y + hh.z * bq.z + hh.w * bq.w;
      g2 += hh.x * c.x + hh.y * c.y + hh.z * c.z + hh.w * c.w;
    }
    float i0 = pv * wi0 + bi0;
    float i1 = pv * wi1 + bi1;
    float i2 = pv * wi2 + bi2;
    float r = 1.f / (1.f + expf(-(i0 + g0)));
    float z = 1.f / (1.f + expf(-(i1 + g1)));
    float nn = tanhf(i2 + r * g2);
    float hn = (1.f - z) * nn + z * hv;
    h[(size_t)row * E + l] = hn;
    u[(size_t)row * E + l] = hn;
  }
}

// ---------------- finish (last step only) ----------------
__global__ __launch_bounds__(256) void finish_kernel(
    const float* __restrict__ gpre2, const float* __restrict__ stats2,
    const float* __restrict__ gamma2, const float* __restrict__ beta2,
    const float* __restrict__ outw, const float* __restrict__ outb,
    const float* __restrict__ sent, const float* __restrict__ ow01,
    float* __restrict__ dout, int t) {
  int tid = threadIdx.x, w = tid >> 6, l = tid & 63;
  int wid = blockIdx.x * 4 + w, nw = gridDim.x * 4;
  float wv = outw[l];
  for (int row = wid; row < BN; row += nw) {
    int n = row % N;
    float m = stats2[n] * (1.f / 2048.f);
    float var = stats2[N + n] * (1.f / 2048.f) - m * m;
    float rstd = rsqrtf(var + 1e-5f);
    float o = (gpre2[(size_t)row * E + l] - m) * rstd * gamma2[n] + beta2[n];
    float tt = o * wv;
#pragma unroll
    for (int off = 32; off; off >>= 1) tt += __shfl_xor(tt, off);
    if (l == 0) {
      float v = outb[0] + sent[row] * ow01[row] + sent[BN + row] * ow01[BN + row]
              + sent[2 * BN + row] * tt;
      int b = row / N;
      dout[((size_t)b * S + t) * N + (row - b * N)] = v;
    }
  }
}

extern "C" void kernel_launch(void* const* d_in, const int* in_sizes, int n_in,
                              void* d_out, int out_size, void* d_ws, size_t ws_size,
                              hipStream_t stream) {
  const float* hidden   = (const float*)d_in[0];
  const float* supports = (const float*)d_in[1];
  const float* memory   = (const float*)d_in[3];
  const float* nv1      = (const float*)d_in[4];
  const float* nv2      = (const float*)d_in[5];
  const float* wih      = (const float*)d_in[6];
  const float* whh      = (const float*)d_in[7];
  const float* bih      = (const float*)d_in[8];
  const float* bhh      = (const float*)d_in[9];
  const float* sent_w   = (const float*)d_in[10];
  const float* gamma    = (const float*)d_in[11];
  const float* beta     = (const float*)d_in[12];
  const float* gw       = (const float*)d_in[13];
  const float* gb       = (const float*)d_in[14];
  const float* outw     = (const float*)d_in[15];
  const float* outb     = (const float*)d_in[16];
  float* out = (float*)d_out;
  float* ws  = (float*)d_ws;

  size_t o = 0;
  float* adp   = ws + o; o += 105632;
  float* kms   = ws + o; o += (size_t)3 * BNE;
  float* C0b   = ws + o; o += (size_t)3 * BNE;
  float* hbuf  = ws + o; o += (size_t)BNE;
  float* ubuf  = ws + o; o += (size_t)BNE;
  float* u1    = ws + o; o += (size_t)BNE;
  float* uni   = ws + o; o += (size_t)9 * BNE;  // precompute: Zb(3)+t1(3)+t2(3); steps: g0..g2
  float* Zb  = uni;
  float* t1b = uni + (size_t)3 * BNE;
  float* t2b = uni + (size_t)6 * BNE;
  float* g0 = uni, *g1 = uni + BNE, *g2 = uni + (size_t)2 * BNE;
  short* kpackS = (short*)(ws + o); o += 2064384;   // 3*B*21*2*2*512 shorts
  short* zpackS = (short*)(ws + o); o += 2162688;   // 3*B*4*11*2*512 shorts
  float* sentb  = ws + o; o += (size_t)3 * BN;
  float* owb    = ws + o; o += (size_t)2 * BN;
  float* statsb = ws + o; o += (size_t)36 * 650;

  hipMemcpyAsync(hbuf, hidden, sizeof(float) * BNE, hipMemcpyDeviceToDevice, stream);
  hipMemsetAsync(statsb, 0, sizeof(float) * 36 * 650, stream);

  adp_kernel<<<N, 256, 0, stream>>>(nv1, nv2, adp);
  rowmmA_kernel<<<672, 256, 0, stream>>>(memory, sent_w, gw, gb, kms, C0b);
  kpack_kernel<<<3 * B * 21, 128, 0, stream>>>(memory, kpackS);

  for (int a = 0; a < 3; ++a) {
    const float* A = (a == 0) ? supports : (a == 1) ? supports + (size_t)N * N : adp;
    bmmB_kernel<<<3 * B * NRT, 256, 0, stream>>>(A, memory + BNE, t1b);
    rowmmZ_kernel<<<672, 256, 0, stream>>>(t1b, gw, 2 * a + 1, Zb, (a > 0) ? 1 : 0);
    bmmB_kernel<<<3 * B * NRT, 256, 0, stream>>>(A, t1b, t2b);
    rowmmZ_kernel<<<672, 256, 0, stream>>>(t2b, gw, 2 * a + 2, Zb, 1);
  }
  zpack_kernel<<<3 * B * 4, 64, 0, stream>>>(Zb, zpackS);

  for (int t = 0; t < S; ++t) {
    float* st0 = statsb + (size_t)(t * 3 + 0) * 650;
    float* st1 = statsb + (size_t)(t * 3 + 1) * 650;
    float* st2 = statsb + (size_t)(t * 3 + 2) * 650;
    const float* g2prev  = (t == 0) ? nullptr : g2;
    const float* st2prev = (t == 0) ? nullptr : statsb + (size_t)((t - 1) * 3 + 2) * 650;
    gru_kernel<<<512, 256, 0, stream>>>(hbuf, g2prev, st2prev, gamma + 2 * N, beta + 2 * N,
                                        outw, outb, sentb, owb, out, t - 1,
                                        wih, whh, bih, bhh, ubuf);
    attn_kernel<<<B * 11, 512, 0, stream>>>(
        ubuf, nullptr, nullptr, nullptr, nullptr, outw, nullptr, nullptr,
        kms, kpackS, zpackS, C0b, g0, st0, sentb);
    attn_kernel<<<B * 11, 512, 0, stream>>>(
        ubuf, g0, st0, gamma, beta, outw, u1, owb,
        kms + BNE, kpackS + (size_t)B * 21 * 2048, zpackS + (size_t)B * 4 * 11 * 1024,
        C0b + BNE, g1, st1, sentb + BN);
    attn_kernel<<<B * 11, 512, 0, stream>>>(
        u1, g1, st1, gamma + N, beta + N, outw, nullptr, owb + BN,
        kms + (size_t)2 * BNE, kpackS + (size_t)2 * B * 21 * 2048,
        zpackS + (size_t)2 * B * 4 * 11 * 1024,
        C0b + (size_t)2 * BNE, g2, st2, sentb + (size_t)2 * BN);
  }
  finish_kernel<<<256, 256, 0, stream>>>(g2, statsb + (size_t)(11 * 3 + 2) * 650,
                                         gamma + 2 * N, beta + 2 * N,
                                         outw, outb, sentb, owb, out, S - 1);
}

// Round 7
// 2096.704 us; speedup vs baseline: 3.6723x; 1.0989x over previous
//
#include <hip/hip_runtime.h>

constexpr int B = 32, N = 325, E = 64, S = 12, HOPS = 3;
constexpr int BN  = B * N;          // 10400
constexpr int BNE = B * N * E;      // 665600
constexpr int EP  = E + 4;
constexpr int PBSTR = 360;          // prob bf16 stride (11 ksteps * 32 = 352 used)
constexpr float SCALE_INV = 0.125f;

typedef __attribute__((ext_vector_type(8))) short short8v;
typedef __attribute__((ext_vector_type(4))) float f32x4;

__device__ inline short f2bf(float f) {
  unsigned x = __builtin_bit_cast(unsigned, f);
  return (short)((x + 0x7FFFu + ((x >> 16) & 1u)) >> 16);
}
__device__ inline float bf2f(short h) {
  unsigned x = ((unsigned)(unsigned short)h) << 16;
  return __builtin_bit_cast(float, x);
}

// ---------------- adp = softmax(relu(nv1 @ nv2^T)) ----------------
__global__ __launch_bounds__(256) void adp_kernel(const float* __restrict__ nv1,
                                                  const float* __restrict__ nv2,
                                                  float* __restrict__ adp) {
  int n = blockIdx.x;
  __shared__ float row[E];
  __shared__ float buf[N];
  __shared__ float red[256];
  int tid = threadIdx.x;
  if (tid < E) row[tid] = nv1[n * E + tid];
  __syncthreads();
  float lmax = -1e30f;
  for (int m = tid; m < N; m += 256) {
    const float* v2 = nv2 + (size_t)m * E;
    float s = 0.f;
#pragma unroll
    for (int e = 0; e < E; ++e) s += row[e] * v2[e];
    s = fmaxf(s, 0.f);
    buf[m] = s;
    lmax = fmaxf(lmax, s);
  }
  red[tid] = lmax;
  __syncthreads();
  for (int off = 128; off > 0; off >>= 1) {
    if (tid < off) red[tid] = fmaxf(red[tid], red[tid + off]);
    __syncthreads();
  }
  float mx = red[0];
  __syncthreads();
  float lsum = 0.f;
  for (int m = tid; m < N; m += 256) {
    float ev = expf(buf[m] - mx);
    buf[m] = ev;
    lsum += ev;
  }
  red[tid] = lsum;
  __syncthreads();
  for (int off = 128; off > 0; off >>= 1) {
    if (tid < off) red[tid] += red[tid + off];
    __syncthreads();
  }
  float inv = 1.f / red[0];
  for (int m = tid; m < N; m += 256) adp[(size_t)n * N + m] = buf[m] * inv;
}

// ---------------- rowmm body: out[r][e'] (+)= in[r][e] W[e][e'] ----------------
__device__ inline void rowmm_body(const float* __restrict__ in, const float* __restrict__ W,
                                  const float* __restrict__ bias, float* __restrict__ out,
                                  int accum, int blk, int nblk) {
  __shared__ float Wl[E][E + 1];
  __shared__ float rbuf[4][4][E];
  int tid = threadIdx.x, w = tid >> 6, l = tid & 63;
  for (int idx = tid; idx < E * E; idx += 256) Wl[idx >> 6][idx & 63] = W[idx];
  __syncthreads();
  float bv = bias ? bias[l] : 0.f;
  constexpr int NG = BN / 16; // 650
  for (int g = blk; g < NG; g += nblk) {
    int base = g * 16 + w * 4;
#pragma unroll
    for (int rr = 0; rr < 4; ++rr) rbuf[w][rr][l] = in[(size_t)(base + rr) * E + l];
    float acc[4];
#pragma unroll
    for (int rr = 0; rr < 4; ++rr)
      acc[rr] = accum ? out[(size_t)(base + rr) * E + l] : bv;
#pragma unroll
    for (int k = 0; k < 16; ++k) {
      float w0 = Wl[4 * k][l], w1 = Wl[4 * k + 1][l], w2 = Wl[4 * k + 2][l], w3 = Wl[4 * k + 3][l];
#pragma unroll
      for (int rr = 0; rr < 4; ++rr) {
        float4 rv = *(const float4*)&rbuf[w][rr][4 * k];
        acc[rr] += rv.x * w0 + rv.y * w1 + rv.z * w2 + rv.w * w3;
      }
    }
#pragma unroll
    for (int rr = 0; rr < 4; ++rr) out[(size_t)(base + rr) * E + l] = acc[rr];
  }
}

// 6 combos: c<3 -> kms[c]; c>=3 -> C0[h]
__global__ __launch_bounds__(256) void rowmmA_kernel(const float* __restrict__ memory,
                                                     const float* __restrict__ sent_w,
                                                     const float* __restrict__ gw,
                                                     const float* __restrict__ gb,
                                                     float* __restrict__ kms,
                                                     float* __restrict__ C0) {
  int c = blockIdx.x / 112, blk = blockIdx.x % 112;
  const float *in, *W, *bias;
  float* out;
  if (c < 3) {
    in = memory + (size_t)c * BNE; W = sent_w + (size_t)c * E * E; bias = nullptr;
    out = kms + (size_t)c * BNE;
  } else {
    int h = c - 3;
    in = memory + (size_t)(h + 1) * BNE; W = gw + (size_t)h * 7 * E * E; bias = gb + h * E;
    out = C0 + (size_t)h * BNE;
  }
  rowmm_body(in, W, bias, out, 0, blk, 112);
}

__global__ __launch_bounds__(256) void rowmmZ_kernel(const float* __restrict__ tbase,
                                                     const float* __restrict__ gw,
                                                     int chunk, float* __restrict__ Zb,
                                                     int accum) {
  int h = blockIdx.x / 224, blk = blockIdx.x % 224;
  rowmm_body(tbase + (size_t)h * BNE, gw + (size_t)h * 7 * E * E + (size_t)chunk * E * E,
             nullptr, Zb + (size_t)h * BNE, accum, blk, 224);
}

// ---------------- pack support matrix into MFMA A-fragments (hi/lo) ----------------
// A[n][m]: A-frag lane l holds row n = nt*16+(l&15), k(m) = ks*32+(l>>4)*8+j
// layout: [(a*21+nt)*11 + ks][part(2)][lane(64)][8]
__global__ __launch_bounds__(64) void apack_kernel(const float* __restrict__ supports,
                                                   const float* __restrict__ adp,
                                                   short* __restrict__ ap) {
  int blk = blockIdx.x;        // a*21 + nt
  int nt = blk % 21, a = blk / 21;
  const float* A = (a < 2) ? supports + (size_t)a * N * N : adp;
  int l = threadIdx.x;
  int row = nt * 16 + (l & 15);
  int k0 = (l >> 4) * 8;
  for (int ks = 0; ks < 11; ++ks) {
    short8v hi, lo;
#pragma unroll
    for (int j = 0; j < 8; ++j) {
      int m = ks * 32 + k0 + j;
      float f = (row < N && m < N) ? A[(size_t)row * N + m] : 0.f;
      short h = f2bf(f);
      hi[j] = h;
      lo[j] = f2bf(f - bf2f(h));
    }
    size_t base = ((size_t)(blk * 11 + ks) * 2) * 512 + (size_t)l * 8;
    *(short8v*)(ap + base) = hi;
    *(short8v*)(ap + base + 512) = lo;
  }
}

// ---------------- pack (3*B) x N x E fp32 into MFMA B-fragments (hi/lo) ----------------
// layout: [(hb*4+et)*11 + ks][part(2)][lane(64)][8]; elem X[m=ks*32+(l>>4)*8+j][e=et*16+(l&15)]
__global__ __launch_bounds__(64) void zpack_kernel(const float* __restrict__ Zb,
                                                   short* __restrict__ zp) {
  int idx = blockIdx.x;          // hb*4 + et
  int et = idx & 3, hb = idx >> 2;
  int l = threadIdx.x;
  int e = et * 16 + (l & 15);
  int mbase = (l >> 4) * 8;
  const float* Zp = Zb + (size_t)hb * N * E;
  for (int ks = 0; ks < 11; ++ks) {
    short8v hi, lo;
#pragma unroll
    for (int j = 0; j < 8; ++j) {
      int m = ks * 32 + mbase + j;
      float f = (m < N) ? Zp[(size_t)m * E + e] : 0.f;
      short h = f2bf(f);
      hi[j] = h;
      lo[j] = f2bf(f - bf2f(h));
    }
    size_t base = ((size_t)idx * 11 + ks) * 1024 + (size_t)l * 8;
    *(short8v*)(zp + base) = hi;
    *(short8v*)(zp + base + 512) = lo;
  }
}

// ---------------- MFMA bmm: out[hb][n][e] = sum_m A[n][m] X[hb][m][e] ----------------
// grid = 96*21; block 256 (wave w = et)
__global__ __launch_bounds__(256) void bmmM_kernel(const short* __restrict__ ap,
                                                   const short* __restrict__ xp,
                                                   float* __restrict__ out) {
  int blk = blockIdx.x;
  int nt = blk % 21, hb = blk / 21;
  int tid = threadIdx.x, w = tid >> 6, l = tid & 63;
  const short8v* apf = (const short8v*)ap;
  const short8v* xpf = (const short8v*)(xp + (((size_t)hb * 4 + w) * 11) * 1024);
  f32x4 acc = {0.f, 0.f, 0.f, 0.f};
#pragma unroll
  for (int ks = 0; ks < 11; ++ks) {
    short8v ah = apf[((nt * 11 + ks) * 2 + 0) * 64 + l];
    short8v al = apf[((nt * 11 + ks) * 2 + 1) * 64 + l];
    short8v xh = xpf[(ks * 2 + 0) * 64 + l];
    short8v xl = xpf[(ks * 2 + 1) * 64 + l];
    acc = __builtin_amdgcn_mfma_f32_16x16x32_bf16(ah, xh, acc, 0, 0, 0);
    acc = __builtin_amdgcn_mfma_f32_16x16x32_bf16(ah, xl, acc, 0, 0, 0);
    acc = __builtin_amdgcn_mfma_f32_16x16x32_bf16(al, xh, acc, 0, 0, 0);
  }
  int row = nt * 16 + (l >> 4) * 4, col = w * 16 + (l & 15);
  float* o = out + (size_t)hb * N * E;
#pragma unroll
  for (int r = 0; r < 4; ++r)
    if (row + r < N) o[(size_t)(row + r) * E + col] = acc[r];
}

// ---------------- pack key into MFMA B-fragments (hi/lo bf16 split) ----------------
__global__ __launch_bounds__(128) void kpack_kernel(const float* __restrict__ memory,
                                                    short* __restrict__ kp) {
  int idx = blockIdx.x;          // (hop*B+b)*21 + ct
  int ct = idx % 21, hb = idx / 21;
  int tid = threadIdx.x, ks = tid >> 6, l = tid & 63;
  int m = ct * 16 + (l & 15);
  int e0 = ks * 32 + (l >> 4) * 8;
  short8v hi, lo;
  if (m < N) {
    const float* p = memory + ((size_t)hb * N + m) * E + e0;
#pragma unroll
    for (int j = 0; j < 8; ++j) {
      float f = p[j];
      short h = f2bf(f);
      hi[j] = h;
      lo[j] = f2bf(f - bf2f(h));
    }
  } else {
#pragma unroll
    for (int j = 0; j < 8; ++j) { hi[j] = 0; lo[j] = 0; }
  }
  size_t base = ((size_t)idx * 2 + ks) * 1024 + (size_t)l * 8;
  *(short8v*)(kp + base) = hi;
  *(short8v*)(kp + base + 512) = lo;
}

// ---------------- fused attn (512 thr): [bnapply prev] + sentinel + energy MFMA +
//                  in-register softmax + PV MFMA + C0 + stats ----------------
__global__ __launch_bounds__(512) void attn_kernel(
    const float* __restrict__ uPrev, const float* __restrict__ gprePrev,
    const float* __restrict__ statsPrev, const float* __restrict__ gammaPrev,
    const float* __restrict__ betaPrev, const float* __restrict__ outw,
    float* __restrict__ uOut, float* __restrict__ owPrev,
    const float* __restrict__ kms, const short* __restrict__ kp,
    const short* __restrict__ zp, const float* __restrict__ C0,
    float* __restrict__ gpre, float* __restrict__ statsCur,
    float* __restrict__ sent) {
  int b = blockIdx.x / 11, rt = blockIdx.x % 11;
  int n0 = rt * 32, nrows = min(32, N - n0);
  int tid = threadIdx.x, w = tid >> 6, l = tid & 63;
  __shared__ float uT[32][68];
  __shared__ short pb[32][PBSTR];
  __shared__ float rowred[32][8];
  __shared__ float rmax[32];
  __shared__ float rsinv[32];
  size_t rowbase = (size_t)b * N + n0;
  int g = l >> 4;

  // zero pb pad cols [336, PBSTR)
  for (int idx = tid; idx < 32 * (PBSTR - 336); idx += 512) {
    int r = idx / (PBSTR - 336), c = idx - r * (PBSTR - 336);
    pb[r][336 + c] = 0;
  }
  // prologue: u rows (+ fused bnapply of previous hop); 4 rows/wave
#pragma unroll
  for (int rr = 0; rr < 4; ++rr) {
    int r = w * 4 + rr;
    if (r < nrows) {
      size_t gi = (rowbase + r) * E + l;
      float uv;
      if (gprePrev) {
        int n = n0 + r;
        float m = statsPrev[n] * (1.f / 2048.f);
        float var = statsPrev[N + n] * (1.f / 2048.f) - m * m;
        float rstd = rsqrtf(var + 1e-5f);
        float o = (gprePrev[gi] - m) * rstd * gammaPrev[n] + betaPrev[n];
        uv = uPrev[gi] + o;
        if (uOut) uOut[gi] = uv;
        float tt = o * outw[l];
#pragma unroll
        for (int off = 32; off; off >>= 1) tt += __shfl_xor(tt, off);
        if (l == 0) owPrev[rowbase + r] = tt;
      } else {
        uv = uPrev[gi];
      }
      uT[r][l] = uv;
    } else {
      uT[r][l] = 0.f;
    }
  }
  __syncthreads();
  // sentinel
#pragma unroll
  for (int rr = 0; rr < 4; ++rr) {
    int r = w * 4 + rr;
    if (r < nrows) {
      float v = uT[r][l] * kms[(rowbase + r) * E + l];
#pragma unroll
      for (int off = 32; off; off >>= 1) v += __shfl_xor(v, off);
      if (l == 0) sent[rowbase + r] = v * SCALE_INV;
    }
  }
  // A fragments (hi/lo split)
  short8v ah[2][2], al[2][2];
  {
    int arow = l & 15, ak = g * 8;
#pragma unroll
    for (int mt = 0; mt < 2; ++mt)
#pragma unroll
      for (int ks = 0; ks < 2; ++ks) {
        const float* p = &uT[mt * 16 + arow][ks * 32 + ak];
        short8v h, lo;
#pragma unroll
        for (int j = 0; j < 8; ++j) {
          float f = p[j];
          short hh = f2bf(f);
          h[j] = hh;
          lo[j] = f2bf(f - bf2f(hh));
        }
        ah[mt][ks] = h; al[mt][ks] = lo;
      }
  }
  // energy: wave handles ct = w, w+8, w+16 (3-term hi/lo MFMA)
  const short8v* kpb = (const short8v*)(kp + (size_t)b * 21 * 2048);
  f32x4 acc0[3], acc1[3];
#pragma unroll
  for (int i = 0; i < 3; ++i) {
    acc0[i] = (f32x4){0.f, 0.f, 0.f, 0.f};
    acc1[i] = (f32x4){0.f, 0.f, 0.f, 0.f};
    int ct = w + 8 * i;
    if (ct < 21) {
      short8v bh0 = kpb[(ct * 4 + 0) * 64 + l];
      short8v bl0 = kpb[(ct * 4 + 1) * 64 + l];
      short8v bh1 = kpb[(ct * 4 + 2) * 64 + l];
      short8v bl1 = kpb[(ct * 4 + 3) * 64 + l];
      f32x4 a0 = acc0[i], a1 = acc1[i];
      a0 = __builtin_amdgcn_mfma_f32_16x16x32_bf16(ah[0][0], bh0, a0, 0, 0, 0);
      a0 = __builtin_amdgcn_mfma_f32_16x16x32_bf16(ah[0][0], bl0, a0, 0, 0, 0);
      a0 = __builtin_amdgcn_mfma_f32_16x16x32_bf16(al[0][0], bh0, a0, 0, 0, 0);
      a0 = __builtin_amdgcn_mfma_f32_16x16x32_bf16(ah[0][1], bh1, a0, 0, 0, 0);
      a0 = __builtin_amdgcn_mfma_f32_16x16x32_bf16(ah[0][1], bl1, a0, 0, 0, 0);
      a0 = __builtin_amdgcn_mfma_f32_16x16x32_bf16(al[0][1], bh1, a0, 0, 0, 0);
      a1 = __builtin_amdgcn_mfma_f32_16x16x32_bf16(ah[1][0], bh0, a1, 0, 0, 0);
      a1 = __builtin_amdgcn_mfma_f32_16x16x32_bf16(ah[1][0], bl0, a1, 0, 0, 0);
      a1 = __builtin_amdgcn_mfma_f32_16x16x32_bf16(al[1][0], bh0, a1, 0, 0, 0);
      a1 = __builtin_amdgcn_mfma_f32_16x16x32_bf16(ah[1][1], bh1, a1, 0, 0, 0);
      a1 = __builtin_amdgcn_mfma_f32_16x16x32_bf16(ah[1][1], bl1, a1, 0, 0, 0);
      a1 = __builtin_amdgcn_mfma_f32_16x16x32_bf16(al[1][1], bh1, a1, 0, 0, 0);
      acc0[i] = a0; acc1[i] = a1;
    }
  }
  // per-row partial max
  {
    float m0[4], m1[4];
#pragma unroll
    for (int r = 0; r < 4; ++r) {
      float a = -1e30f, c = -1e30f;
#pragma unroll
      for (int i = 0; i < 3; ++i)
        if (w + 8 * i < 21) { a = fmaxf(a, acc0[i][r]); c = fmaxf(c, acc1[i][r]); }
#pragma unroll
      for (int off = 1; off < 16; off <<= 1) {
        a = fmaxf(a, __shfl_xor(a, off));
        c = fmaxf(c, __shfl_xor(c, off));
      }
      m0[r] = a; m1[r] = c;
    }
    if ((l & 15) == 0) {
#pragma unroll
      for (int r = 0; r < 4; ++r) {
        rowred[g * 4 + r][w] = m0[r];
        rowred[16 + g * 4 + r][w] = m1[r];
      }
    }
  }
  __syncthreads();
  if (tid < 32) {
    float a = rowred[tid][0];
#pragma unroll
    for (int j = 1; j < 8; ++j) a = fmaxf(a, rowred[tid][j]);
    rmax[tid] = a;
  }
  __syncthreads();
  // exp + bf16 round + partial sums (denominator = sum of bf16-rounded probs)
  {
    float mx0[4], mx1[4], s0[4], s1[4];
#pragma unroll
    for (int r = 0; r < 4; ++r) {
      mx0[r] = rmax[g * 4 + r]; mx1[r] = rmax[16 + g * 4 + r];
      s0[r] = 0.f; s1[r] = 0.f;
    }
#pragma unroll
    for (int i = 0; i < 3; ++i) {
      int ct = w + 8 * i;
      if (ct < 21) {
        int col = ct * 16 + (l & 15);
        bool valid = col < N;
#pragma unroll
        for (int r = 0; r < 4; ++r) {
          short pv0 = 0, pv1 = 0;
          if (valid) {
            pv0 = f2bf(expf((acc0[i][r] - mx0[r]) * SCALE_INV));
            pv1 = f2bf(expf((acc1[i][r] - mx1[r]) * SCALE_INV));
            s0[r] += bf2f(pv0);
            s1[r] += bf2f(pv1);
          }
          pb[g * 4 + r][col] = pv0;
          pb[16 + g * 4 + r][col] = pv1;
        }
      }
    }
#pragma unroll
    for (int r = 0; r < 4; ++r) {
#pragma unroll
      for (int off = 1; off < 16; off <<= 1) {
        s0[r] += __shfl_xor(s0[r], off);
        s1[r] += __shfl_xor(s1[r], off);
      }
    }
    if ((l & 15) == 0) {
#pragma unroll
      for (int r = 0; r < 4; ++r) {
        rowred[g * 4 + r][w] = s0[r];
        rowred[16 + g * 4 + r][w] = s1[r];
      }
    }
  }
  __syncthreads();
  if (tid < 32) {
    float s = 0.f;
#pragma unroll
    for (int j = 0; j < 8; ++j) s += rowred[tid][j];
    rsinv[tid] = 1.f / s;
  }
  __syncthreads();
  // PV: wave -> (mt = w>>2, et = w&3); Z hi/lo
  int mt = w >> 2, et = w & 3;
  const short8v* zpb = (const short8v*)(zp + (size_t)b * 4 * 11 * 1024);
  f32x4 acc = {0.f, 0.f, 0.f, 0.f};
  {
    int arow = mt * 16 + (l & 15), ak = g * 8;
#pragma unroll
    for (int ks = 0; ks < 11; ++ks) {
      short8v a = *(const short8v*)&pb[arow][ks * 32 + ak];
      short8v zh = zpb[((et * 11 + ks) * 2 + 0) * 64 + l];
      short8v zl = zpb[((et * 11 + ks) * 2 + 1) * 64 + l];
      acc = __builtin_amdgcn_mfma_f32_16x16x32_bf16(a, zh, acc, 0, 0, 0);
      acc = __builtin_amdgcn_mfma_f32_16x16x32_bf16(a, zl, acc, 0, 0, 0);
    }
  }
  // epilogue: gpre = acc/rsum + C0; stats via 16-lane reduce + atomics
  int colA = et * 16 + (l & 15);
#pragma unroll
  for (int r = 0; r < 4; ++r) {
    int row = mt * 16 + g * 4 + r;
    float sval = 0.f, qval = 0.f;
    if (row < nrows) {
      size_t gi = (rowbase + row) * E + colA;
      float gA = acc[r] * rsinv[row] + C0[gi];
      gpre[gi] = gA;
      sval = gA; qval = gA * gA;
    }
#pragma unroll
    for (int off = 1; off < 16; off <<= 1) {
      sval += __shfl_xor(sval, off);
      qval += __shfl_xor(qval, off);
    }
    if ((l & 15) == 0 && row < nrows) {
      atomicAdd(&statsCur[n0 + row], sval);
      atomicAdd(&statsCur[N + n0 + row], qval);
    }
  }
}

// ---------------- GRU cell with fused finish of previous step ----------------
__global__ __launch_bounds__(256) void gru_kernel(
    float* __restrict__ h,
    const float* __restrict__ gpre2, const float* __restrict__ stats2,
    const float* __restrict__ gamma2, const float* __restrict__ beta2,
    const float* __restrict__ outw, const float* __restrict__ outb,
    const float* __restrict__ sentb, const float* __restrict__ owb,
    float* __restrict__ dout, int tprev,
    const float* __restrict__ wih, const float* __restrict__ whh,
    const float* __restrict__ bih, const float* __restrict__ bhh,
    float* __restrict__ u) {
  __shared__ float W[3 * E][EP];
  __shared__ float hrow[4][E];
  int tid = threadIdx.x, w = tid >> 6, l = tid & 63;
  for (int idx = tid; idx < 3 * E * E; idx += 256) W[idx >> 6][idx & 63] = whh[idx];
  __syncthreads();
  float wi0 = wih[l], wi1 = wih[64 + l], wi2 = wih[128 + l];
  float bi0 = bih[l], bi1 = bih[64 + l], bi2 = bih[128 + l];
  float bh0 = bhh[l], bh1 = bhh[64 + l], bh2 = bhh[128 + l];
  float wv = outw[l];
  float ob = outb[0];
  int nw = gridDim.x * 4, wid = blockIdx.x * 4 + w;
  for (int row = wid; row < BN; row += nw) {
    float hv = h[(size_t)row * E + l];
    hrow[w][l] = hv;
    float pv = 0.f;
    if (gpre2) {  // fused finish of step tprev
      int n = row % N;
      float m = stats2[n] * (1.f / 2048.f);
      float var = stats2[N + n] * (1.f / 2048.f) - m * m;
      float rstd = rsqrtf(var + 1e-5f);
      float o = (gpre2[(size_t)row * E + l] - m) * rstd * gamma2[n] + beta2[n];
      float tt = o * wv;
#pragma unroll
      for (int off = 32; off; off >>= 1) tt += __shfl_xor(tt, off);
      float v = ob + sentb[row] * owb[row] + sentb[BN + row] * owb[BN + row]
              + sentb[2 * BN + row] * tt;
      pv = v;
      if (l == 0) {
        int bb = row / N;
        dout[((size_t)bb * S + tprev) * N + (row - bb * N)] = v;
      }
    }
    float g0 = bh0, g1 = bh1, g2 = bh2;
#pragma unroll
    for (int k = 0; k < 16; ++k) {
      float4 hh = *(const float4*)&hrow[w][4 * k];
      float4 a = *(const float4*)&W[l][4 * k];
      float4 bq = *(const float4*)&W[64 + l][4 * k];
      float4 c = *(const float4*)&W[128 + l][4 * k];
      g0 += hh.x * a.x + hh.y * a.y + hh.z * a.z + hh.w * a.w;
      g1 += hh.x * bq.x + hh.y * bq.y + hh.z * bq.z + hh.w * bq.w;
      g2 += hh.x * c.x + hh.y * c.y + hh.z * c.z + hh.w * c.w;
    }
    float i0 = pv * wi0 + bi0;
    float i1 = pv * wi1 + bi1;
    float i2 = pv * wi2 + bi2;
    float r = 1.f / (1.f + expf(-(i0 + g0)));
    float z = 1.f / (1.f + expf(-(i1 + g1)));
    float nn = tanhf(i2 + r * g2);
    float hn = (1.f - z) * nn + z * hv;
    h[(size_t)row * E + l] = hn;
    u[(size_t)row * E + l] = hn;
  }
}

// ---------------- finish (last step only) ----------------
__global__ __launch_bounds__(256) void finish_kernel(
    const float* __restrict__ gpre2, const float* __restrict__ stats2,
    const float* __restrict__ gamma2, const float* __restrict__ beta2,
    const float* __restrict__ outw, const float* __restrict__ outb,
    const float* __restrict__ sent, const float* __restrict__ ow01,
    float* __restrict__ dout, int t) {
  int tid = threadIdx.x, w = tid >> 6, l = tid & 63;
  int wid = blockIdx.x * 4 + w, nw = gridDim.x * 4;
  float wv = outw[l];
  for (int row = wid; row < BN; row += nw) {
    int n = row % N;
    float m = stats2[n] * (1.f / 2048.f);
    float var = stats2[N + n] * (1.f / 2048.f) - m * m;
    float rstd = rsqrtf(var + 1e-5f);
    float o = (gpre2[(size_t)row * E + l] - m) * rstd * gamma2[n] + beta2[n];
    float tt = o * wv;
#pragma unroll
    for (int off = 32; off; off >>= 1) tt += __shfl_xor(tt, off);
    if (l == 0) {
      float v = outb[0] + sent[row] * ow01[row] + sent[BN + row] * ow01[BN + row]
              + sent[2 * BN + row] * tt;
      int b = row / N;
      dout[((size_t)b * S + t) * N + (row - b * N)] = v;
    }
  }
}

extern "C" void kernel_launch(void* const* d_in, const int* in_sizes, int n_in,
                              void* d_out, int out_size, void* d_ws, size_t ws_size,
                              hipStream_t stream) {
  const float* hidden   = (const float*)d_in[0];
  const float* supports = (const float*)d_in[1];
  const float* memory   = (const float*)d_in[3];
  const float* nv1      = (const float*)d_in[4];
  const float* nv2      = (const float*)d_in[5];
  const float* wih      = (const float*)d_in[6];
  const float* whh      = (const float*)d_in[7];
  const float* bih      = (const float*)d_in[8];
  const float* bhh      = (const float*)d_in[9];
  const float* sent_w   = (const float*)d_in[10];
  const float* gamma    = (const float*)d_in[11];
  const float* beta     = (const float*)d_in[12];
  const float* gw       = (const float*)d_in[13];
  const float* gb       = (const float*)d_in[14];
  const float* outw     = (const float*)d_in[15];
  const float* outb     = (const float*)d_in[16];
  float* out = (float*)d_out;
  float* ws  = (float*)d_ws;

  size_t o = 0;
  float* adp   = ws + o; o += 105632;
  float* kms   = ws + o; o += (size_t)3 * BNE;
  float* C0b   = ws + o; o += (size_t)3 * BNE;
  float* hbuf  = ws + o; o += (size_t)BNE;
  float* ubuf  = ws + o; o += (size_t)BNE;
  float* u1    = ws + o; o += (size_t)BNE;
  float* uni   = ws + o; o += (size_t)9 * BNE;  // precompute: Zb(3)+t1(3)+t2(3); steps: g0..g2
  float* Zb  = uni;
  float* t1b = uni + (size_t)3 * BNE;
  float* t2b = uni + (size_t)6 * BNE;
  float* g0 = uni, *g1 = uni + BNE, *g2 = uni + (size_t)2 * BNE;
  short* kpackS = (short*)(ws + o); o += 2064384;   // 3*B*21*2*2*512 shorts
  short* zpackS = (short*)(ws + o); o += 2162688;   // 3*B*4*11*2*512 shorts
  short* apackS = (short*)(ws + o); o += 354816;    // 3*21*11*2*512 shorts
  short* xp0    = (short*)(ws + o); o += 2162688;   // packed memory[1..3]
  short* xp1    = (short*)(ws + o); o += 2162688;   // packed t1 (per support)
  float* sentb  = ws + o; o += (size_t)3 * BN;
  float* owb    = ws + o; o += (size_t)2 * BN;
  float* statsb = ws + o; o += (size_t)36 * 650;

  hipMemcpyAsync(hbuf, hidden, sizeof(float) * BNE, hipMemcpyDeviceToDevice, stream);
  hipMemsetAsync(statsb, 0, sizeof(float) * 36 * 650, stream);

  adp_kernel<<<N, 256, 0, stream>>>(nv1, nv2, adp);
  rowmmA_kernel<<<672, 256, 0, stream>>>(memory, sent_w, gw, gb, kms, C0b);
  kpack_kernel<<<3 * B * 21, 128, 0, stream>>>(memory, kpackS);
  apack_kernel<<<63, 64, 0, stream>>>(supports, adp, apackS);
  zpack_kernel<<<3 * B * 4, 64, 0, stream>>>(memory + BNE, xp0);  // pack x = memory[1..3]

  for (int a = 0; a < 3; ++a) {
    const short* apA = apackS + (size_t)a * 21 * 11 * 2 * 512;
    bmmM_kernel<<<96 * 21, 256, 0, stream>>>(apA, xp0, t1b);
    rowmmZ_kernel<<<672, 256, 0, stream>>>(t1b, gw, 2 * a + 1, Zb, (a > 0) ? 1 : 0);
    zpack_kernel<<<3 * B * 4, 64, 0, stream>>>(t1b, xp1);
    bmmM_kernel<<<96 * 21, 256, 0, stream>>>(apA, xp1, t2b);
    rowmmZ_kernel<<<672, 256, 0, stream>>>(t2b, gw, 2 * a + 2, Zb, 1);
  }
  zpack_kernel<<<3 * B * 4, 64, 0, stream>>>(Zb, zpackS);

  for (int t = 0; t < S; ++t) {
    float* st0 = statsb + (size_t)(t * 3 + 0) * 650;
    float* st1 = statsb + (size_t)(t * 3 + 1) * 650;
    float* st2 = statsb + (size_t)(t * 3 + 2) * 650;
    const float* g2prev  = (t == 0) ? nullptr : g2;
    const float* st2prev = (t == 0) ? nullptr : statsb + (size_t)((t - 1) * 3 + 2) * 650;
    gru_kernel<<<512, 256, 0, stream>>>(hbuf, g2prev, st2prev, gamma + 2 * N, beta + 2 * N,
                                        outw, outb, sentb, owb, out, t - 1,
                                        wih, whh, bih, bhh, ubuf);
    attn_kernel<<<B * 11, 512, 0, stream>>>(
        ubuf, nullptr, nullptr, nullptr, nullptr, outw, nullptr, nullptr,
        kms, kpackS, zpackS, C0b, g0, st0, sentb);
    attn_kernel<<<B * 11, 512, 0, stream>>>(
        ubuf, g0, st0, gamma, beta, outw, u1, owb,
        kms + BNE, kpackS + (size_t)B * 21 * 2048, zpackS + (size_t)B * 4 * 11 * 1024,
        C0b + BNE, g1, st1, sentb + BN);
    attn_kernel<<<B * 11, 512, 0, stream>>>(
        u1, g1, st1, gamma + N, beta + N, outw, nullptr, owb + BN,
        kms + (size_t)2 * BNE, kpackS + (size_t)2 * B * 21 * 2048,
        zpackS + (size_t)2 * B * 4 * 11 * 1024,
        C0b + (size_t)2 * BNE, g2, st2, sentb + (size_t)2 * BN);
  }
  finish_kernel<<<256, 256, 0, stream>>>(g2, statsb + (size_t)(11 * 3 + 2) * 650,
                                         gamma + 2 * N, beta + 2 * N,
                                         outw, outb, sentb, owb, out, S - 1);
}

// Round 8
// 2060.336 us; speedup vs baseline: 3.7371x; 1.0177x over previous
//
#include <hip/hip_runtime.h>

constexpr int B = 32, N = 325, E = 64, S = 12, HOPS = 3;
constexpr int BN  = B * N;          // 10400
constexpr int BNE = B * N * E;      // 665600
constexpr int EP  = E + 4;
constexpr int PBSTR = 360;          // prob bf16 stride (11 ksteps * 32 = 352 used)
constexpr float SCALE_INV = 0.125f;

typedef __attribute__((ext_vector_type(8))) short short8v;
typedef __attribute__((ext_vector_type(4))) float f32x4;

__device__ inline short f2bf(float f) {
  unsigned x = __builtin_bit_cast(unsigned, f);
  return (short)((x + 0x7FFFu + ((x >> 16) & 1u)) >> 16);
}
__device__ inline float bf2f(short h) {
  unsigned x = ((unsigned)(unsigned short)h) << 16;
  return __builtin_bit_cast(float, x);
}

// ---------------- adp = softmax(relu(nv1 @ nv2^T)) ----------------
__global__ __launch_bounds__(256) void adp_kernel(const float* __restrict__ nv1,
                                                  const float* __restrict__ nv2,
                                                  float* __restrict__ adp) {
  int n = blockIdx.x;
  __shared__ float row[E];
  __shared__ float buf[N];
  __shared__ float red[256];
  int tid = threadIdx.x;
  if (tid < E) row[tid] = nv1[n * E + tid];
  __syncthreads();
  float lmax = -1e30f;
  for (int m = tid; m < N; m += 256) {
    const float* v2 = nv2 + (size_t)m * E;
    float s = 0.f;
#pragma unroll
    for (int e = 0; e < E; ++e) s += row[e] * v2[e];
    s = fmaxf(s, 0.f);
    buf[m] = s;
    lmax = fmaxf(lmax, s);
  }
  red[tid] = lmax;
  __syncthreads();
  for (int off = 128; off > 0; off >>= 1) {
    if (tid < off) red[tid] = fmaxf(red[tid], red[tid + off]);
    __syncthreads();
  }
  float mx = red[0];
  __syncthreads();
  float lsum = 0.f;
  for (int m = tid; m < N; m += 256) {
    float ev = expf(buf[m] - mx);
    buf[m] = ev;
    lsum += ev;
  }
  red[tid] = lsum;
  __syncthreads();
  for (int off = 128; off > 0; off >>= 1) {
    if (tid < off) red[tid] += red[tid + off];
    __syncthreads();
  }
  float inv = 1.f / red[0];
  for (int m = tid; m < N; m += 256) adp[(size_t)n * N + m] = buf[m] * inv;
}

// ---------------- rowmm body: out[r][e'] (+)= in[r][e] W[e][e'] ----------------
__device__ inline void rowmm_body(const float* __restrict__ in, const float* __restrict__ W,
                                  const float* __restrict__ bias, float* __restrict__ out,
                                  int accum, int blk, int nblk) {
  __shared__ float Wl[E][E + 1];
  __shared__ float rbuf[4][4][E];
  int tid = threadIdx.x, w = tid >> 6, l = tid & 63;
  for (int idx = tid; idx < E * E; idx += 256) Wl[idx >> 6][idx & 63] = W[idx];
  __syncthreads();
  float bv = bias ? bias[l] : 0.f;
  constexpr int NG = BN / 16; // 650
  for (int g = blk; g < NG; g += nblk) {
    int base = g * 16 + w * 4;
#pragma unroll
    for (int rr = 0; rr < 4; ++rr) rbuf[w][rr][l] = in[(size_t)(base + rr) * E + l];
    float acc[4];
#pragma unroll
    for (int rr = 0; rr < 4; ++rr)
      acc[rr] = accum ? out[(size_t)(base + rr) * E + l] : bv;
#pragma unroll
    for (int k = 0; k < 16; ++k) {
      float w0 = Wl[4 * k][l], w1 = Wl[4 * k + 1][l], w2 = Wl[4 * k + 2][l], w3 = Wl[4 * k + 3][l];
#pragma unroll
      for (int rr = 0; rr < 4; ++rr) {
        float4 rv = *(const float4*)&rbuf[w][rr][4 * k];
        acc[rr] += rv.x * w0 + rv.y * w1 + rv.z * w2 + rv.w * w3;
      }
    }
#pragma unroll
    for (int rr = 0; rr < 4; ++rr) out[(size_t)(base + rr) * E + l] = acc[rr];
  }
}

// 6 combos: c<3 -> kms[c]; c>=3 -> C0[h]
__global__ __launch_bounds__(256) void rowmmA_kernel(const float* __restrict__ memory,
                                                     const float* __restrict__ sent_w,
                                                     const float* __restrict__ gw,
                                                     const float* __restrict__ gb,
                                                     float* __restrict__ kms,
                                                     float* __restrict__ C0) {
  int c = blockIdx.x / 112, blk = blockIdx.x % 112;
  const float *in, *W, *bias;
  float* out;
  if (c < 3) {
    in = memory + (size_t)c * BNE; W = sent_w + (size_t)c * E * E; bias = nullptr;
    out = kms + (size_t)c * BNE;
  } else {
    int h = c - 3;
    in = memory + (size_t)(h + 1) * BNE; W = gw + (size_t)h * 7 * E * E; bias = gb + h * E;
    out = C0 + (size_t)h * BNE;
  }
  rowmm_body(in, W, bias, out, 0, blk, 112);
}

__global__ __launch_bounds__(256) void rowmmZ_kernel(const float* __restrict__ tbase,
                                                     const float* __restrict__ gw,
                                                     int chunk, float* __restrict__ Zb,
                                                     int accum) {
  int h = blockIdx.x / 224, blk = blockIdx.x % 224;
  rowmm_body(tbase + (size_t)h * BNE, gw + (size_t)h * 7 * E * E + (size_t)chunk * E * E,
             nullptr, Zb + (size_t)h * BNE, accum, blk, 224);
}

// ---------------- pack support matrix into MFMA A-fragments (hi/lo) ----------------
__global__ __launch_bounds__(64) void apack_kernel(const float* __restrict__ supports,
                                                   const float* __restrict__ adp,
                                                   short* __restrict__ ap) {
  int blk = blockIdx.x;        // a*21 + nt
  int nt = blk % 21, a = blk / 21;
  const float* A = (a < 2) ? supports + (size_t)a * N * N : adp;
  int l = threadIdx.x;
  int row = nt * 16 + (l & 15);
  int k0 = (l >> 4) * 8;
  for (int ks = 0; ks < 11; ++ks) {
    short8v hi, lo;
#pragma unroll
    for (int j = 0; j < 8; ++j) {
      int m = ks * 32 + k0 + j;
      float f = (row < N && m < N) ? A[(size_t)row * N + m] : 0.f;
      short h = f2bf(f);
      hi[j] = h;
      lo[j] = f2bf(f - bf2f(h));
    }
    size_t base = ((size_t)(blk * 11 + ks) * 2) * 512 + (size_t)l * 8;
    *(short8v*)(ap + base) = hi;
    *(short8v*)(ap + base + 512) = lo;
  }
}

// ---------------- pack (3*B) x N x E fp32 into MFMA B-fragments (hi/lo) ----------------
__global__ __launch_bounds__(64) void zpack_kernel(const float* __restrict__ Zb,
                                                   short* __restrict__ zp) {
  int idx = blockIdx.x;          // hb*4 + et
  int et = idx & 3, hb = idx >> 2;
  int l = threadIdx.x;
  int e = et * 16 + (l & 15);
  int mbase = (l >> 4) * 8;
  const float* Zp = Zb + (size_t)hb * N * E;
  for (int ks = 0; ks < 11; ++ks) {
    short8v hi, lo;
#pragma unroll
    for (int j = 0; j < 8; ++j) {
      int m = ks * 32 + mbase + j;
      float f = (m < N) ? Zp[(size_t)m * E + e] : 0.f;
      short h = f2bf(f);
      hi[j] = h;
      lo[j] = f2bf(f - bf2f(h));
    }
    size_t base = ((size_t)idx * 11 + ks) * 1024 + (size_t)l * 8;
    *(short8v*)(zp + base) = hi;
    *(short8v*)(zp + base + 512) = lo;
  }
}

// ---------------- MFMA bmm: out[hb][n][e] = sum_m A[n][m] X[hb][m][e] ----------------
// grid = 96*21; XCD-swizzled so the 21 nt-blocks of one hb share an XCD (L2 reuse of xp)
__global__ __launch_bounds__(256) void bmmM_kernel(const short* __restrict__ ap,
                                                   const short* __restrict__ xp,
                                                   float* __restrict__ out) {
  int bid = blockIdx.x;
  int x8 = bid & 7, q = bid >> 3;            // wgid%8 -> XCD
  int nt = q % 21, hbhi = q / 21;
  int hb = hbhi * 8 + x8;                    // hb%8 == wgid%8
  int tid = threadIdx.x, w = tid >> 6, l = tid & 63;
  const short8v* apf = (const short8v*)ap;
  const short8v* xpf = (const short8v*)(xp + (((size_t)hb * 4 + w) * 11) * 1024);
  f32x4 acc = {0.f, 0.f, 0.f, 0.f};
#pragma unroll
  for (int ks = 0; ks < 11; ++ks) {
    short8v ah = apf[((nt * 11 + ks) * 2 + 0) * 64 + l];
    short8v al = apf[((nt * 11 + ks) * 2 + 1) * 64 + l];
    short8v xh = xpf[(ks * 2 + 0) * 64 + l];
    short8v xl = xpf[(ks * 2 + 1) * 64 + l];
    acc = __builtin_amdgcn_mfma_f32_16x16x32_bf16(ah, xh, acc, 0, 0, 0);
    acc = __builtin_amdgcn_mfma_f32_16x16x32_bf16(ah, xl, acc, 0, 0, 0);
    acc = __builtin_amdgcn_mfma_f32_16x16x32_bf16(al, xh, acc, 0, 0, 0);
  }
  int row = nt * 16 + (l >> 4) * 4, col = w * 16 + (l & 15);
  float* o = out + (size_t)hb * N * E;
#pragma unroll
  for (int r = 0; r < 4; ++r)
    if (row + r < N) o[(size_t)(row + r) * E + col] = acc[r];
}

// ---------------- pack key into MFMA B-fragments (hi/lo bf16 split) ----------------
__global__ __launch_bounds__(128) void kpack_kernel(const float* __restrict__ memory,
                                                    short* __restrict__ kp) {
  int idx = blockIdx.x;          // (hop*B+b)*21 + ct
  int ct = idx % 21, hb = idx / 21;
  int tid = threadIdx.x, ks = tid >> 6, l = tid & 63;
  int m = ct * 16 + (l & 15);
  int e0 = ks * 32 + (l >> 4) * 8;
  short8v hi, lo;
  if (m < N) {
    const float* p = memory + ((size_t)hb * N + m) * E + e0;
#pragma unroll
    for (int j = 0; j < 8; ++j) {
      float f = p[j];
      short h = f2bf(f);
      hi[j] = h;
      lo[j] = f2bf(f - bf2f(h));
    }
  } else {
#pragma unroll
    for (int j = 0; j < 8; ++j) { hi[j] = 0; lo[j] = 0; }
  }
  size_t base = ((size_t)idx * 2 + ks) * 1024 + (size_t)l * 8;
  *(short8v*)(kp + base) = hi;
  *(short8v*)(kp + base + 512) = lo;
}

// ---------------- fused attn (512 thr): XCD-swizzled; [bnapply prev] + sentinel +
//                  energy MFMA + in-register softmax + PV MFMA + C0 + stats ----------------
__global__ __launch_bounds__(512) void attn_kernel(
    const float* __restrict__ uPrev, const float* __restrict__ gprePrev,
    const float* __restrict__ statsPrev, const float* __restrict__ gammaPrev,
    const float* __restrict__ betaPrev, const float* __restrict__ outw,
    float* __restrict__ uOut, float* __restrict__ owPrev,
    const float* __restrict__ kms, const short* __restrict__ kp,
    const short* __restrict__ zp, const float* __restrict__ C0,
    float* __restrict__ gpre, float* __restrict__ statsCur,
    float* __restrict__ sent) {
  // XCD swizzle: all 11 rt-blocks of batch b share wgid%8 -> same XCD L2 caches kp/zp[b]
  int bid = blockIdx.x;
  int x8 = bid & 7, q = bid >> 3;            // q in [0,44)
  int rt = q % 11, bhi = q / 11;
  int b = bhi * 8 + x8;
  int n0 = rt * 32, nrows = min(32, N - n0);
  int tid = threadIdx.x, w = tid >> 6, l = tid & 63;
  __shared__ float uT[32][68];
  __shared__ short pb[32][PBSTR];
  __shared__ float rowred[32][8];
  __shared__ float rmax[32];
  __shared__ float rsinv[32];
  size_t rowbase = (size_t)b * N + n0;
  int g = l >> 4;

  // zero pb pad cols [336, PBSTR)
  for (int idx = tid; idx < 32 * (PBSTR - 336); idx += 512) {
    int r = idx / (PBSTR - 336), c = idx - r * (PBSTR - 336);
    pb[r][336 + c] = 0;
  }
  // prologue: u rows (+ fused bnapply of previous hop); 4 rows/wave
#pragma unroll
  for (int rr = 0; rr < 4; ++rr) {
    int r = w * 4 + rr;
    if (r < nrows) {
      size_t gi = (rowbase + r) * E + l;
      float uv;
      if (gprePrev) {
        int n = n0 + r;
        float m = statsPrev[n] * (1.f / 2048.f);
        float var = statsPrev[N + n] * (1.f / 2048.f) - m * m;
        float rstd = rsqrtf(var + 1e-5f);
        float o = (gprePrev[gi] - m) * rstd * gammaPrev[n] + betaPrev[n];
        uv = uPrev[gi] + o;
        if (uOut) uOut[gi] = uv;
        float tt = o * outw[l];
#pragma unroll
        for (int off = 32; off; off >>= 1) tt += __shfl_xor(tt, off);
        if (l == 0) owPrev[rowbase + r] = tt;
      } else {
        uv = uPrev[gi];
      }
      uT[r][l] = uv;
    } else {
      uT[r][l] = 0.f;
    }
  }
  __syncthreads();
  // sentinel
#pragma unroll
  for (int rr = 0; rr < 4; ++rr) {
    int r = w * 4 + rr;
    if (r < nrows) {
      float v = uT[r][l] * kms[(rowbase + r) * E + l];
#pragma unroll
      for (int off = 32; off; off >>= 1) v += __shfl_xor(v, off);
      if (l == 0) sent[rowbase + r] = v * SCALE_INV;
    }
  }
  // A fragments (hi/lo split)
  short8v ah[2][2], al[2][2];
  {
    int arow = l & 15, ak = g * 8;
#pragma unroll
    for (int mt = 0; mt < 2; ++mt)
#pragma unroll
      for (int ks = 0; ks < 2; ++ks) {
        const float* p = &uT[mt * 16 + arow][ks * 32 + ak];
        short8v h, lo;
#pragma unroll
        for (int j = 0; j < 8; ++j) {
          float f = p[j];
          short hh = f2bf(f);
          h[j] = hh;
          lo[j] = f2bf(f - bf2f(hh));
        }
        ah[mt][ks] = h; al[mt][ks] = lo;
      }
  }
  // energy: wave handles ct = w, w+8, w+16 (3-term hi/lo MFMA)
  const short8v* kpb = (const short8v*)(kp + (size_t)b * 21 * 2048);
  f32x4 acc0[3], acc1[3];
#pragma unroll
  for (int i = 0; i < 3; ++i) {
    acc0[i] = (f32x4){0.f, 0.f, 0.f, 0.f};
    acc1[i] = (f32x4){0.f, 0.f, 0.f, 0.f};
    int ct = w + 8 * i;
    if (ct < 21) {
      short8v bh0 = kpb[(ct * 4 + 0) * 64 + l];
      short8v bl0 = kpb[(ct * 4 + 1) * 64 + l];
      short8v bh1 = kpb[(ct * 4 + 2) * 64 + l];
      short8v bl1 = kpb[(ct * 4 + 3) * 64 + l];
      f32x4 a0 = acc0[i], a1 = acc1[i];
      a0 = __builtin_amdgcn_mfma_f32_16x16x32_bf16(ah[0][0], bh0, a0, 0, 0, 0);
      a0 = __builtin_amdgcn_mfma_f32_16x16x32_bf16(ah[0][0], bl0, a0, 0, 0, 0);
      a0 = __builtin_amdgcn_mfma_f32_16x16x32_bf16(al[0][0], bh0, a0, 0, 0, 0);
      a0 = __builtin_amdgcn_mfma_f32_16x16x32_bf16(ah[0][1], bh1, a0, 0, 0, 0);
      a0 = __builtin_amdgcn_mfma_f32_16x16x32_bf16(ah[0][1], bl1, a0, 0, 0, 0);
      a0 = __builtin_amdgcn_mfma_f32_16x16x32_bf16(al[0][1], bh1, a0, 0, 0, 0);
      a1 = __builtin_amdgcn_mfma_f32_16x16x32_bf16(ah[1][0], bh0, a1, 0, 0, 0);
      a1 = __builtin_amdgcn_mfma_f32_16x16x32_bf16(ah[1][0], bl0, a1, 0, 0, 0);
      a1 = __builtin_amdgcn_mfma_f32_16x16x32_bf16(al[1][0], bh0, a1, 0, 0, 0);
      a1 = __builtin_amdgcn_mfma_f32_16x16x32_bf16(ah[1][1], bh1, a1, 0, 0, 0);
      a1 = __builtin_amdgcn_mfma_f32_16x16x32_bf16(ah[1][1], bl1, a1, 0, 0, 0);
      a1 = __builtin_amdgcn_mfma_f32_16x16x32_bf16(al[1][1], bh1, a1, 0, 0, 0);
      acc0[i] = a0; acc1[i] = a1;
    }
  }
  // per-row partial max
  {
    float m0[4], m1[4];
#pragma unroll
    for (int r = 0; r < 4; ++r) {
      float a = -1e30f, c = -1e30f;
#pragma unroll
      for (int i = 0; i < 3; ++i)
        if (w + 8 * i < 21) { a = fmaxf(a, acc0[i][r]); c = fmaxf(c, acc1[i][r]); }
#pragma unroll
      for (int off = 1; off < 16; off <<= 1) {
        a = fmaxf(a, __shfl_xor(a, off));
        c = fmaxf(c, __shfl_xor(c, off));
      }
      m0[r] = a; m1[r] = c;
    }
    if ((l & 15) == 0) {
#pragma unroll
      for (int r = 0; r < 4; ++r) {
        rowred[g * 4 + r][w] = m0[r];
        rowred[16 + g * 4 + r][w] = m1[r];
      }
    }
  }
  __syncthreads();
  if (tid < 32) {
    float a = rowred[tid][0];
#pragma unroll
    for (int j = 1; j < 8; ++j) a = fmaxf(a, rowred[tid][j]);
    rmax[tid] = a;
  }
  __syncthreads();
  // exp + bf16 round + partial sums (denominator = sum of bf16-rounded probs)
  {
    float mx0[4], mx1[4], s0[4], s1[4];
#pragma unroll
    for (int r = 0; r < 4; ++r) {
      mx0[r] = rmax[g * 4 + r]; mx1[r] = rmax[16 + g * 4 + r];
      s0[r] = 0.f; s1[r] = 0.f;
    }
#pragma unroll
    for (int i = 0; i < 3; ++i) {
      int ct = w + 8 * i;
      if (ct < 21) {
        int col = ct * 16 + (l & 15);
        bool valid = col < N;
#pragma unroll
        for (int r = 0; r < 4; ++r) {
          short pv0 = 0, pv1 = 0;
          if (valid) {
            pv0 = f2bf(expf((acc0[i][r] - mx0[r]) * SCALE_INV));
            pv1 = f2bf(expf((acc1[i][r] - mx1[r]) * SCALE_INV));
            s0[r] += bf2f(pv0);
            s1[r] += bf2f(pv1);
          }
          pb[g * 4 + r][col] = pv0;
          pb[16 + g * 4 + r][col] = pv1;
        }
      }
    }
#pragma unroll
    for (int r = 0; r < 4; ++r) {
#pragma unroll
      for (int off = 1; off < 16; off <<= 1) {
        s0[r] += __shfl_xor(s0[r], off);
        s1[r] += __shfl_xor(s1[r], off);
      }
    }
    if ((l & 15) == 0) {
#pragma unroll
      for (int r = 0; r < 4; ++r) {
        rowred[g * 4 + r][w] = s0[r];
        rowred[16 + g * 4 + r][w] = s1[r];
      }
    }
  }
  __syncthreads();
  if (tid < 32) {
    float s = 0.f;
#pragma unroll
    for (int j = 0; j < 8; ++j) s += rowred[tid][j];
    rsinv[tid] = 1.f / s;
  }
  __syncthreads();
  // PV: wave -> (mt = w>>2, et = w&3); Z hi/lo
  int mt = w >> 2, et = w & 3;
  const short8v* zpb = (const short8v*)(zp + (size_t)b * 4 * 11 * 1024);
  f32x4 acc = {0.f, 0.f, 0.f, 0.f};
  {
    int arow = mt * 16 + (l & 15), ak = g * 8;
#pragma unroll
    for (int ks = 0; ks < 11; ++ks) {
      short8v a = *(const short8v*)&pb[arow][ks * 32 + ak];
      short8v zh = zpb[((et * 11 + ks) * 2 + 0) * 64 + l];
      short8v zl = zpb[((et * 11 + ks) * 2 + 1) * 64 + l];
      acc = __builtin_amdgcn_mfma_f32_16x16x32_bf16(a, zh, acc, 0, 0, 0);
      acc = __builtin_amdgcn_mfma_f32_16x16x32_bf16(a, zl, acc, 0, 0, 0);
    }
  }
  // epilogue: gpre = acc/rsum + C0; stats via 16-lane reduce + atomics
  int colA = et * 16 + (l & 15);
#pragma unroll
  for (int r = 0; r < 4; ++r) {
    int row = mt * 16 + g * 4 + r;
    float sval = 0.f, qval = 0.f;
    if (row < nrows) {
      size_t gi = (rowbase + row) * E + colA;
      float gA = acc[r] * rsinv[row] + C0[gi];
      gpre[gi] = gA;
      sval = gA; qval = gA * gA;
    }
#pragma unroll
    for (int off = 1; off < 16; off <<= 1) {
      sval += __shfl_xor(sval, off);
      qval += __shfl_xor(qval, off);
    }
    if ((l & 15) == 0 && row < nrows) {
      atomicAdd(&statsCur[n0 + row], sval);
      atomicAdd(&statsCur[N + n0 + row], qval);
    }
  }
}

// ---------------- GRU cell with fused finish of previous step ----------------
__global__ __launch_bounds__(256) void gru_kernel(
    float* __restrict__ h,
    const float* __restrict__ gpre2, const float* __restrict__ stats2,
    const float* __restrict__ gamma2, const float* __restrict__ beta2,
    const float* __restrict__ outw, const float* __restrict__ outb,
    const float* __restrict__ sentb, const float* __restrict__ owb,
    float* __restrict__ dout, int tprev,
    const float* __restrict__ wih, const float* __restrict__ whh,
    const float* __restrict__ bih, const float* __restrict__ bhh,
    float* __restrict__ u) {
  __shared__ float W[3 * E][EP];
  __shared__ float hrow[4][E];
  int tid = threadIdx.x, w = tid >> 6, l = tid & 63;
  for (int idx = tid; idx < 3 * E * E; idx += 256) W[idx >> 6][idx & 63] = whh[idx];
  __syncthreads();
  float wi0 = wih[l], wi1 = wih[64 + l], wi2 = wih[128 + l];
  float bi0 = bih[l], bi1 = bih[64 + l], bi2 = bih[128 + l];
  float bh0 = bhh[l], bh1 = bhh[64 + l], bh2 = bhh[128 + l];
  float wv = outw[l];
  float ob = outb[0];
  int nw = gridDim.x * 4, wid = blockIdx.x * 4 + w;
  for (int row = wid; row < BN; row += nw) {
    float hv = h[(size_t)row * E + l];
    hrow[w][l] = hv;
    float pv = 0.f;
    if (gpre2) {  // fused finish of step tprev
      int n = row % N;
      float m = stats2[n] * (1.f / 2048.f);
      float var = stats2[N + n] * (1.f / 2048.f) - m * m;
      float rstd = rsqrtf(var + 1e-5f);
      float o = (gpre2[(size_t)row * E + l] - m) * rstd * gamma2[n] + beta2[n];
      float tt = o * wv;
#pragma unroll
      for (int off = 32; off; off >>= 1) tt += __shfl_xor(tt, off);
      float v = ob + sentb[row] * owb[row] + sentb[BN + row] * owb[BN + row]
              + sentb[2 * BN + row] * tt;
      pv = v;
      if (l == 0) {
        int bb = row / N;
        dout[((size_t)bb * S + tprev) * N + (row - bb * N)] = v;
      }
    }
    float g0 = bh0, g1 = bh1, g2 = bh2;
#pragma unroll
    for (int k = 0; k < 16; ++k) {
      float4 hh = *(const float4*)&hrow[w][4 * k];
      float4 a = *(const float4*)&W[l][4 * k];
      float4 bq = *(const float4*)&W[64 + l][4 * k];
      float4 c = *(const float4*)&W[128 + l][4 * k];
      g0 += hh.x * a.x + hh.y * a.y + hh.z * a.z + hh.w * a.w;
      g1 += hh.x * bq.x + hh.y * bq.y + hh.z * bq.z + hh.w * bq.w;
      g2 += hh.x * c.x + hh.y * c.y + hh.z * c.z + hh.w * c.w;
    }
    float i0 = pv * wi0 + bi0;
    float i1 = pv * wi1 + bi1;
    float i2 = pv * wi2 + bi2;
    float r = 1.f / (1.f + expf(-(i0 + g0)));
    float z = 1.f / (1.f + expf(-(i1 + g1)));
    float nn = tanhf(i2 + r * g2);
    float hn = (1.f - z) * nn + z * hv;
    h[(size_t)row * E + l] = hn;
    u[(size_t)row * E + l] = hn;
  }
}

// ---------------- finish (last step only) ----------------
__global__ __launch_bounds__(256) void finish_kernel(
    const float* __restrict__ gpre2, const float* __restrict__ stats2,
    const float* __restrict__ gamma2, const float* __restrict__ beta2,
    const float* __restrict__ outw, const float* __restrict__ outb,
    const float* __restrict__ sent, const float* __restrict__ ow01,
    float* __restrict__ dout, int t) {
  int tid = threadIdx.x, w = tid >> 6, l = tid & 63;
  int wid = blockIdx.x * 4 + w, nw = gridDim.x * 4;
  float wv = outw[l];
  for (int row = wid; row < BN; row += nw) {
    int n = row % N;
    float m = stats2[n] * (1.f / 2048.f);
    float var = stats2[N + n] * (1.f / 2048.f) - m * m;
    float rstd = rsqrtf(var + 1e-5f);
    float o = (gpre2[(size_t)row * E + l] - m) * rstd * gamma2[n] + beta2[n];
    float tt = o * wv;
#pragma unroll
    for (int off = 32; off; off >>= 1) tt += __shfl_xor(tt, off);
    if (l == 0) {
      float v = outb[0] + sent[row] * ow01[row] + sent[BN + row] * ow01[BN + row]
              + sent[2 * BN + row] * tt;
      int b = row / N;
      dout[((size_t)b * S + t) * N + (row - b * N)] = v;
    }
  }
}

extern "C" void kernel_launch(void* const* d_in, const int* in_sizes, int n_in,
                              void* d_out, int out_size, void* d_ws, size_t ws_size,
                              hipStream_t stream) {
  const float* hidden   = (const float*)d_in[0];
  const float* supports = (const float*)d_in[1];
  const float* memory   = (const float*)d_in[3];
  const float* nv1      = (const float*)d_in[4];
  const float* nv2      = (const float*)d_in[5];
  const float* wih      = (const float*)d_in[6];
  const float* whh      = (const float*)d_in[7];
  const float* bih      = (const float*)d_in[8];
  const float* bhh      = (const float*)d_in[9];
  const float* sent_w   = (const float*)d_in[10];
  const float* gamma    = (const float*)d_in[11];
  const float* beta     = (const float*)d_in[12];
  const float* gw       = (const float*)d_in[13];
  const float* gb       = (const float*)d_in[14];
  const float* outw     = (const float*)d_in[15];
  const float* outb     = (const float*)d_in[16];
  float* out = (float*)d_out;
  float* ws  = (float*)d_ws;

  size_t o = 0;
  float* adp   = ws + o; o += 105632;
  float* kms   = ws + o; o += (size_t)3 * BNE;
  float* C0b   = ws + o; o += (size_t)3 * BNE;
  float* hbuf  = ws + o; o += (size_t)BNE;
  float* ubuf  = ws + o; o += (size_t)BNE;
  float* u1    = ws + o; o += (size_t)BNE;
  float* uni   = ws + o; o += (size_t)9 * BNE;  // precompute: Zb(3)+t1(3)+t2(3); steps: g0..g2
  float* Zb  = uni;
  float* t1b = uni + (size_t)3 * BNE;
  float* t2b = uni + (size_t)6 * BNE;
  float* g0 = uni, *g1 = uni + BNE, *g2 = uni + (size_t)2 * BNE;
  short* kpackS = (short*)(ws + o); o += 2064384;   // 3*B*21*2*2*512 shorts
  short* zpackS = (short*)(ws + o); o += 2162688;   // 3*B*4*11*2*512 shorts
  short* apackS = (short*)(ws + o); o += 354816;    // 3*21*11*2*512 shorts
  short* xp0    = (short*)(ws + o); o += 2162688;   // packed memory[1..3]
  short* xp1    = (short*)(ws + o); o += 2162688;   // packed t1 (per support)
  float* sentb  = ws + o; o += (size_t)3 * BN;
  float* owb    = ws + o; o += (size_t)2 * BN;
  float* statsb = ws + o; o += (size_t)36 * 650;

  hipMemcpyAsync(hbuf, hidden, sizeof(float) * BNE, hipMemcpyDeviceToDevice, stream);
  hipMemsetAsync(statsb, 0, sizeof(float) * 36 * 650, stream);

  adp_kernel<<<N, 256, 0, stream>>>(nv1, nv2, adp);
  rowmmA_kernel<<<672, 256, 0, stream>>>(memory, sent_w, gw, gb, kms, C0b);
  kpack_kernel<<<3 * B * 21, 128, 0, stream>>>(memory, kpackS);
  apack_kernel<<<63, 64, 0, stream>>>(supports, adp, apackS);
  zpack_kernel<<<3 * B * 4, 64, 0, stream>>>(memory + BNE, xp0);  // pack x = memory[1..3]

  for (int a = 0; a < 3; ++a) {
    const short* apA = apackS + (size_t)a * 21 * 11 * 2 * 512;
    bmmM_kernel<<<96 * 21, 256, 0, stream>>>(apA, xp0, t1b);
    rowmmZ_kernel<<<672, 256, 0, stream>>>(t1b, gw, 2 * a + 1, Zb, (a > 0) ? 1 : 0);
    zpack_kernel<<<3 * B * 4, 64, 0, stream>>>(t1b, xp1);
    bmmM_kernel<<<96 * 21, 256, 0, stream>>>(apA, xp1, t2b);
    rowmmZ_kernel<<<672, 256, 0, stream>>>(t2b, gw, 2 * a + 2, Zb, 1);
  }
  zpack_kernel<<<3 * B * 4, 64, 0, stream>>>(Zb, zpackS);

  for (int t = 0; t < S; ++t) {
    float* st0 = statsb + (size_t)(t * 3 + 0) * 650;
    float* st1 = statsb + (size_t)(t * 3 + 1) * 650;
    float* st2 = statsb + (size_t)(t * 3 + 2) * 650;
    const float* g2prev  = (t == 0) ? nullptr : g2;
    const float* st2prev = (t == 0) ? nullptr : statsb + (size_t)((t - 1) * 3 + 2) * 650;
    gru_kernel<<<512, 256, 0, stream>>>(hbuf, g2prev, st2prev, gamma + 2 * N, beta + 2 * N,
                                        outw, outb, sentb, owb, out, t - 1,
                                        wih, whh, bih, bhh, ubuf);
    attn_kernel<<<B * 11, 512, 0, stream>>>(
        ubuf, nullptr, nullptr, nullptr, nullptr, outw, nullptr, nullptr,
        kms, kpackS, zpackS, C0b, g0, st0, sentb);
    attn_kernel<<<B * 11, 512, 0, stream>>>(
        ubuf, g0, st0, gamma, beta, outw, u1, owb,
        kms + BNE, kpackS + (size_t)B * 21 * 2048, zpackS + (size_t)B * 4 * 11 * 1024,
        C0b + BNE, g1, st1, sentb + BN);
    attn_kernel<<<B * 11, 512, 0, stream>>>(
        u1, g1, st1, gamma + N, beta + N, outw, nullptr, owb + BN,
        kms + (size_t)2 * BNE, kpackS + (size_t)2 * B * 21 * 2048,
        zpackS + (size_t)2 * B * 4 * 11 * 1024,
        C0b + (size_t)2 * BNE, g2, st2, sentb + (size_t)2 * BN);
  }
  finish_kernel<<<256, 256, 0, stream>>>(g2, statsb + (size_t)(11 * 3 + 2) * 650,
                                         gamma + 2 * N, beta + 2 * N,
                                         outw, outb, sentb, owb, out, S - 1);
}